// Round 5
// baseline (224.967 us; speedup 1.0000x reference)
//
#include <hip/hip_runtime.h>
#include <math.h>

#define EPS 1e-5f

// ---------------------------------------------------------------------------
// Pre-pass: wT4[cq][o] = a3[o] * w3[o][4cq..4cq+4)  (quad-major, BN-scale folded)
//           bias3[o]   = a3[o]*(b3[o]-m3[o]) + be3[o]
// ---------------------------------------------------------------------------
__global__ __launch_bounds__(256) void k_wT(
    const float* __restrict__ w3, const float* __restrict__ b3,
    const float* __restrict__ g3, const float* __restrict__ be3,
    const float* __restrict__ m3, const float* __restrict__ v3,
    float4* __restrict__ wT4, float* __restrict__ bias3)
{
    const int o = blockIdx.x * 256 + threadIdx.x;     // 0..1023
    const float a3 = g3[o] * rsqrtf(v3[o] + EPS);
    const float4* row = (const float4*)(w3 + (size_t)o * 128);
    #pragma unroll
    for (int cq = 0; cq < 32; ++cq) {
        float4 w = row[cq];
        wT4[cq * 1024 + o] = make_float4(a3 * w.x, a3 * w.y, a3 * w.z, a3 * w.w);
    }
    bias3[o] = a3 * (b3[o] - m3[o]) + be3[o];
}

// ---------------------------------------------------------------------------
// Kernel 1: edge-conv (6->64) + BN + ReLU + max over K=520, fused with
//           conv2 (64->128) + BN + ReLU.  ONE WAVE per (b, n); lane = channel.
// d-vectors are wave-uniform -> scalar-path loads (s_load), consumed as the
// SGPR operand of v_fma.  No LDS in the hot loop (was the 39us pipe in R2).
// conv1 = a*(W[:,0:3]*ips + (W[:,3:6]-W[:,0:3])*x + b - m) + be, folded.
// max_k relu(v) = max(0, max_k v).
// blockIdx = n*256 + b  =>  same-b blocks land on the same XCD (L2 locality).
// ---------------------------------------------------------------------------
__global__ __launch_bounds__(64) void k_stage12(
    const float* __restrict__ pts,        // [256,15,3]
    const float* __restrict__ info,       // [256,520,15,3]
    const float* __restrict__ w_info,     // [64,6]
    const float* __restrict__ b_info,
    const float* __restrict__ g_info, const float* __restrict__ be_info,
    const float* __restrict__ m_info, const float* __restrict__ v_info,
    const float* __restrict__ w2,         // [128,64]
    const float* __restrict__ b2,
    const float* __restrict__ g2, const float* __restrict__ be2,
    const float* __restrict__ m2, const float* __restrict__ v2,
    float* __restrict__ h2out)            // [256,15,128]
{
    __shared__ float h1s[64];

    const int tid = threadIdx.x;
    const int b = blockIdx.x & 255;       // XCD-locality swizzle
    const int n = blockIdx.x >> 8;

    const float x0 = pts[(b * 15 + n) * 3 + 0];
    const float x1 = pts[(b * 15 + n) * 3 + 1];
    const float x2 = pts[(b * 15 + n) * 3 + 2];

    // per-lane folded coefficients, o = tid (64 channels, one wave)
    const int o = tid;
    const float w0 = w_info[o * 6 + 0], w1 = w_info[o * 6 + 1], w2c = w_info[o * 6 + 2];
    const float w3 = w_info[o * 6 + 3], w4 = w_info[o * 6 + 4], w5 = w_info[o * 6 + 5];
    const float a  = g_info[o] * rsqrtf(v_info[o] + EPS);
    const float c0 = a * w0, c1 = a * w1, c2 = a * w2c;
    const float bias = a * ((w3 - w0) * x0 + (w4 - w1) * x1 + (w5 - w2c) * x2
                            + b_info[o] - m_info[o]) + be_info[o];

    // wave-uniform base: info[b][k][n][:] at ib + k*45 (4B-aligned scalar loads,
    // same access form the round-2 kernel validated)
    const float* ib = info + (size_t)b * 23400 + n * 3;

    float acc = 0.f;   // relu floor
    #pragma unroll 8
    for (int k = 0; k < 520; ++k) {
        const float* p = ib + k * 45;
        const float d0 = p[0], d1 = p[1], d2 = p[2];
        float v = fmaf(c0, d0, fmaf(c1, d1, fmaf(c2, d2, bias)));
        acc = fmaxf(acc, v);
    }
    h1s[tid] = acc;
    __syncthreads();

    // conv2: 64 -> 128, BN + ReLU.  thread t -> outputs t and t+64.
    float s0 = 0.f, s1 = 0.f;
    const float* wr0 = w2 + tid * 64;
    const float* wr1 = w2 + (tid + 64) * 64;
    #pragma unroll
    for (int q = 0; q < 16; ++q) {
        const float4 h4 = *(const float4*)(h1s + q * 4);    // LDS broadcast (tiny)
        const float4 a4 = *(const float4*)(wr0 + q * 4);
        const float4 b4 = *(const float4*)(wr1 + q * 4);
        s0 = fmaf(a4.x, h4.x, fmaf(a4.y, h4.y, fmaf(a4.z, h4.z, fmaf(a4.w, h4.w, s0))));
        s1 = fmaf(b4.x, h4.x, fmaf(b4.y, h4.y, fmaf(b4.z, h4.z, fmaf(b4.w, h4.w, s1))));
    }
    {
        const int oo = tid;
        const float a2 = g2[oo] * rsqrtf(v2[oo] + EPS);
        float val = a2 * (s0 + b2[oo] - m2[oo]) + be2[oo];
        h2out[((size_t)b * 15 + n) * 128 + oo] = fmaxf(val, 0.f);
    }
    {
        const int oo = tid + 64;
        const float a2 = g2[oo] * rsqrtf(v2[oo] + EPS);
        float val = a2 * (s1 + b2[oo] - m2[oo]) + be2[oo];
        h2out[((size_t)b * 15 + n) * 128 + oo] = fmaxf(val, 0.f);
    }
}

// ---------------------------------------------------------------------------
// Kernel 2: conv3 (128->1024, BN-scale pre-folded into wT4) + global max over N.
// One block per (oq, b); thread = output channel o.  h2[b] row is block-uniform
// -> scalar loads; wT4 reads are fully coalesced (quad-major layout).
// blockIdx = oq*256 + b.
// ---------------------------------------------------------------------------
__global__ __launch_bounds__(256) void k_stage3max(
    const float* __restrict__ h2,     // [256,15,128]
    const float4* __restrict__ wT4,   // [32][1024]
    const float* __restrict__ bias3,  // [1024]
    float* __restrict__ gout)         // [256,1024]
{
    const int tid = threadIdx.x;
    const int b  = blockIdx.x & 255;
    const int oq = blockIdx.x >> 8;
    const int o  = oq * 256 + tid;

    const float* h2b = h2 + (size_t)b * 1920;   // block-uniform

    float acc[15];
    #pragma unroll
    for (int n = 0; n < 15; ++n) acc[n] = 0.f;

    #pragma unroll 4
    for (int cq = 0; cq < 32; ++cq) {
        const float4 w = wT4[cq * 1024 + o];    // coalesced per-lane
        #pragma unroll
        for (int n = 0; n < 15; ++n) {
            const float4 h4 = *(const float4*)(h2b + n * 128 + cq * 4); // uniform, 16B-aligned -> s_load
            acc[n] = fmaf(w.x, h4.x, fmaf(w.y, h4.y,
                     fmaf(w.z, h4.z, fmaf(w.w, h4.w, acc[n]))));
        }
    }
    float mx = -INFINITY;
    #pragma unroll
    for (int n = 0; n < 15; ++n) mx = fmaxf(mx, acc[n]);
    gout[(size_t)b * 1024 + o] = mx + bias3[o];
}

// ---------------------------------------------------------------------------
// FC GEMM: C[m][n] = act(sum_k A[m][k] * W[n][k] + ...)  (unchanged, validated R2)
// ---------------------------------------------------------------------------
template <bool BN_RELU>
__global__ __launch_bounds__(256) void k_fc(
    const float* __restrict__ A, const float* __restrict__ W,
    const float* __restrict__ bias,
    const float* __restrict__ gg, const float* __restrict__ be,
    const float* __restrict__ mm, const float* __restrict__ vv,
    float* __restrict__ C, int K, int Nc)
{
    __shared__ float As[32][33];
    __shared__ float Ws[32][33];

    const int tid = threadIdx.x;
    const int bm = blockIdx.x * 32, bn = blockIdx.y * 32;
    const int ml = (tid >> 4) * 2, nl = (tid & 15) * 2;
    const int row = tid >> 3, kq = (tid & 7) * 4;

    float acc00 = 0.f, acc01 = 0.f, acc10 = 0.f, acc11 = 0.f;

    for (int k0 = 0; k0 < K; k0 += 32) {
        const float4 av = *(const float4*)(A + (size_t)(bm + row) * K + k0 + kq);
        const float4 wv = *(const float4*)(W + (size_t)(bn + row) * K + k0 + kq);
        __syncthreads();
        As[row][kq + 0] = av.x; As[row][kq + 1] = av.y;
        As[row][kq + 2] = av.z; As[row][kq + 3] = av.w;
        Ws[row][kq + 0] = wv.x; Ws[row][kq + 1] = wv.y;
        Ws[row][kq + 2] = wv.z; Ws[row][kq + 3] = wv.w;
        __syncthreads();
        #pragma unroll
        for (int k = 0; k < 32; ++k) {
            const float a0 = As[ml][k], a1 = As[ml + 1][k];
            const float b0 = Ws[nl][k], b1 = Ws[nl + 1][k];
            acc00 = fmaf(a0, b0, acc00); acc01 = fmaf(a0, b1, acc01);
            acc10 = fmaf(a1, b0, acc10); acc11 = fmaf(a1, b1, acc11);
        }
    }

    const int n0 = bn + nl, n1 = n0 + 1;
    float v00, v01, v10, v11;
    if (BN_RELU) {
        const float s0 = gg[n0] * rsqrtf(vv[n0] + EPS);
        const float s1 = gg[n1] * rsqrtf(vv[n1] + EPS);
        const float c0 = s0 * (bias[n0] - mm[n0]) + be[n0];
        const float c1 = s1 * (bias[n1] - mm[n1]) + be[n1];
        v00 = fmaxf(fmaf(s0, acc00, c0), 0.f); v01 = fmaxf(fmaf(s1, acc01, c1), 0.f);
        v10 = fmaxf(fmaf(s0, acc10, c0), 0.f); v11 = fmaxf(fmaf(s1, acc11, c1), 0.f);
    } else {
        v00 = acc00 + bias[n0]; v01 = acc01 + bias[n1];
        v10 = acc10 + bias[n0]; v11 = acc11 + bias[n1];
    }
    float* cr0 = C + (size_t)(bm + ml) * Nc + n0;
    cr0[0] = v00; cr0[1] = v01;
    float* cr1 = C + (size_t)(bm + ml + 1) * Nc + n0;
    cr1[0] = v10; cr1[1] = v11;
}

// ---------------------------------------------------------------------------
extern "C" void kernel_launch(void* const* d_in, const int* in_sizes, int n_in,
                              void* d_out, int out_size, void* d_ws, size_t ws_size,
                              hipStream_t stream)
{
    const float* pts     = (const float*)d_in[0];
    // d_in[1] = label (unused)
    const float* info    = (const float*)d_in[2];
    const float* w_info  = (const float*)d_in[3];
    const float* b_info  = (const float*)d_in[4];
    const float* g_info  = (const float*)d_in[5];
    const float* be_info = (const float*)d_in[6];
    const float* m_info  = (const float*)d_in[7];
    const float* v_info  = (const float*)d_in[8];
    const float* w2      = (const float*)d_in[9];
    const float* b2      = (const float*)d_in[10];
    const float* g2      = (const float*)d_in[11];
    const float* be2     = (const float*)d_in[12];
    const float* m2      = (const float*)d_in[13];
    const float* v2      = (const float*)d_in[14];
    const float* w3      = (const float*)d_in[15];
    const float* b3      = (const float*)d_in[16];
    const float* g3      = (const float*)d_in[17];
    const float* be3     = (const float*)d_in[18];
    const float* m3      = (const float*)d_in[19];
    const float* v3      = (const float*)d_in[20];
    const float* wf1     = (const float*)d_in[21];
    const float* bf1     = (const float*)d_in[22];
    const float* gf1     = (const float*)d_in[23];
    const float* bef1    = (const float*)d_in[24];
    const float* mf1     = (const float*)d_in[25];
    const float* vf1     = (const float*)d_in[26];
    const float* wf2     = (const float*)d_in[27];
    const float* bf2     = (const float*)d_in[28];
    const float* gf2     = (const float*)d_in[29];
    const float* bef2    = (const float*)d_in[30];
    const float* mf2     = (const float*)d_in[31];
    const float* vf2     = (const float*)d_in[32];
    const float* wf3     = (const float*)d_in[33];
    const float* bf3     = (const float*)d_in[34];

    float* ws  = (float*)d_ws;
    float*  h2    = ws;                                 // 491520 floats
    float*  g     = ws + 491520;                        // 262144
    float*  f1    = ws + 491520 + 262144;               // 131072
    float4* wT4   = (float4*)(ws + 491520 + 262144 + 131072);  // 32768 float4
    float*  bias3 = ws + 491520 + 262144 + 131072 + 131072;    // 1024

    float* ret = (float*)d_out;            // [256, 800]
    float* f2  = ret + 256 * 800;          // [256, 256]

    k_wT<<<4, 256, 0, stream>>>(w3, b3, g3, be3, m3, v3, wT4, bias3);

    k_stage12<<<15 * 256, 64, 0, stream>>>(
        pts, info, w_info, b_info, g_info, be_info, m_info, v_info,
        w2, b2, g2, be2, m2, v2, h2);

    k_stage3max<<<4 * 256, 256, 0, stream>>>(h2, wT4, bias3, g);

    k_fc<true><<<dim3(8, 16), 256, 0, stream>>>(
        g, wf1, bf1, gf1, bef1, mf1, vf1, f1, 1024, 512);

    k_fc<true><<<dim3(8, 8), 256, 0, stream>>>(
        f1, wf2, bf2, gf2, bef2, mf2, vf2, f2, 512, 256);

    k_fc<false><<<dim3(8, 25), 256, 0, stream>>>(
        f2, wf3, bf3, nullptr, nullptr, nullptr, nullptr, ret, 256, 800);
}

// Round 6
// 172.055 us; speedup vs baseline: 1.3075x; 1.3075x over previous
//
#include <hip/hip_runtime.h>
#include <math.h>

#define EPS 1e-5f

__device__ __forceinline__ float rlane(float v, int l) {
    return __int_as_float(__builtin_amdgcn_readlane(__float_as_int(v), l));
}

// ---------------------------------------------------------------------------
// Pre-pass: wT4[cq][o] = a3[o] * w3[o][4cq..4cq+4)  (quad-major, BN folded)
//           bias3[o]   = a3[o]*(b3[o]-m3[o]) + be3[o]
// 128 blocks: idx = (cq, o)
// ---------------------------------------------------------------------------
__global__ __launch_bounds__(256) void k_wT(
    const float* __restrict__ w3, const float* __restrict__ b3,
    const float* __restrict__ g3, const float* __restrict__ be3,
    const float* __restrict__ m3, const float* __restrict__ v3,
    float4* __restrict__ wT4, float* __restrict__ bias3)
{
    const int idx = blockIdx.x * 256 + threadIdx.x;   // 0..32767
    const int o  = idx & 1023;
    const int cq = idx >> 10;                         // 0..31
    const float a3 = g3[o] * rsqrtf(v3[o] + EPS);
    const float4 w = *(const float4*)(w3 + (size_t)o * 128 + cq * 4);
    wT4[cq * 1024 + o] = make_float4(a3 * w.x, a3 * w.y, a3 * w.z, a3 * w.w);
    if (cq == 0) bias3[o] = a3 * (b3[o] - m3[o]) + be3[o];
}

// ---------------------------------------------------------------------------
// Kernel 1: edge-conv (6->64) + BN + ReLU + max over K=520 + conv2 (64->128)
// + BN + ReLU.  ONE BLOCK PER b (1024 thr, 16 waves).  Wave w handles
// k = w, w+16, ...  Lanes 0..44 cooperatively load the 180B row
// info[b][k][*][*] with ONE coalesced dword instruction; d-components are
// broadcast to all 64 o-lanes via v_readlane (compile-time index).
// SMEM streaming (R5: 130us) and LDS-bcast (R2: 39us) both avoided.
// conv1 = c·ips + bias(n), all BN folded; max_k relu = relu(max_k).
// ---------------------------------------------------------------------------
__global__ __launch_bounds__(1024) void k_stage12(
    const float* __restrict__ pts,        // [256,15,3]
    const float* __restrict__ info,       // [256,520,15,3]
    const float* __restrict__ w_info,     // [64,6]
    const float* __restrict__ b_info,
    const float* __restrict__ g_info, const float* __restrict__ be_info,
    const float* __restrict__ m_info, const float* __restrict__ v_info,
    const float* __restrict__ w2,         // [128,64]
    const float* __restrict__ b2,
    const float* __restrict__ g2, const float* __restrict__ be2,
    const float* __restrict__ m2, const float* __restrict__ v2,
    float* __restrict__ h2out)            // [256,15,128]
{
    __shared__ float part[16][15][64];    // 61440 B
    __shared__ float h1s[15][64];         // 3840 B  (total 65280 <= 64KB)

    const int tid  = threadIdx.x;
    const int b    = blockIdx.x;
    const int wave = tid >> 6;
    const int lane = tid & 63;
    const int o    = lane;

    // folded coefficients for channel o
    const float w0 = w_info[o * 6 + 0], w1 = w_info[o * 6 + 1], w2c = w_info[o * 6 + 2];
    const float w3 = w_info[o * 6 + 3], w4 = w_info[o * 6 + 4], w5  = w_info[o * 6 + 5];
    const float a  = g_info[o] * rsqrtf(v_info[o] + EPS);
    const float c0 = a * w0, c1 = a * w1, c2 = a * w2c;
    const float q  = a * (w3 - w0), r = a * (w4 - w1), s = a * (w5 - w2c);
    const float t  = a * (b_info[o] - m_info[o]) + be_info[o];

    float bias[15];
    #pragma unroll
    for (int n = 0; n < 15; ++n) {
        const float x0 = pts[b * 45 + n * 3 + 0];
        const float x1 = pts[b * 45 + n * 3 + 1];
        const float x2 = pts[b * 45 + n * 3 + 2];
        bias[n] = fmaf(q, x0, fmaf(r, x1, fmaf(s, x2, t)));
    }

    float acc[15];
    #pragma unroll
    for (int n = 0; n < 15; ++n) acc[n] = 0.f;   // relu floor

    const float* rowbase = info + (size_t)b * 23400;
    const bool ld = (lane < 45);

    #pragma unroll 4
    for (int k = wave; k < 520; k += 16) {
        float rv = 0.f;
        if (ld) rv = rowbase[k * 45 + lane];      // one coalesced dword / wave
        #pragma unroll
        for (int n = 0; n < 15; ++n) {
            float v = fmaf(c0, rlane(rv, n * 3 + 0),
                      fmaf(c1, rlane(rv, n * 3 + 1),
                      fmaf(c2, rlane(rv, n * 3 + 2), bias[n])));
            acc[n] = fmaxf(acc[n], v);
        }
    }

    #pragma unroll
    for (int n = 0; n < 15; ++n) part[wave][n][o] = acc[n];
    __syncthreads();

    if (tid < 960) {
        const int n = tid >> 6, oo = tid & 63;
        float m = part[0][n][oo];
        #pragma unroll
        for (int w = 1; w < 16; ++w) m = fmaxf(m, part[w][n][oo]);
        h1s[n][oo] = m;
    }
    __syncthreads();

    // conv2: 15*128 outputs; waves are n-uniform (128 | 1024)
    for (int idx = tid; idx < 1920; idx += 1024) {
        const int n = idx >> 7, o2 = idx & 127;
        const float* wr = w2 + o2 * 64;
        float sacc = 0.f;
        #pragma unroll
        for (int qd = 0; qd < 16; ++qd) {
            const float4 h4 = *(const float4*)(&h1s[n][qd * 4]);  // LDS bcast
            const float4 a4 = *(const float4*)(wr + qd * 4);
            sacc = fmaf(a4.x, h4.x, fmaf(a4.y, h4.y,
                   fmaf(a4.z, h4.z, fmaf(a4.w, h4.w, sacc))));
        }
        const float a2 = g2[o2] * rsqrtf(v2[o2] + EPS);
        const float val = a2 * (sacc + b2[o2] - m2[o2]) + be2[o2];
        h2out[((size_t)b * 15 + n) * 128 + o2] = fmaxf(val, 0.f);
    }
}

// ---------------------------------------------------------------------------
// Kernel 2: conv3 (128->1024, scale folded in wT4) + global max over N=15.
// One block per b, 512 threads; thread handles o and o+512 (2 fma per
// broadcast h-value -> VMEM issue halved, ~balanced with VALU).
// h-row loads forced onto the VECTOR path via opaque-zero VGPR index
// (prevents the R5 SMEM-scalarization disaster); float4 units keep 16B align.
// ---------------------------------------------------------------------------
__global__ __launch_bounds__(512) void k_stage3max(
    const float* __restrict__ h2,     // [256,15,128]
    const float4* __restrict__ wT4,   // [32][1024]
    const float* __restrict__ bias3,  // [1024]
    float* __restrict__ gout)         // [256,1024]
{
    const int tid = threadIdx.x;
    const int b   = blockIdx.x;
    const int o0  = tid, o1 = tid + 512;

    int kz = 0;
    asm volatile("" : "+v"(kz));                       // opaque 0 in a VGPR
    const float4* hb4 = (const float4*)(h2 + (size_t)b * 1920) + kz;

    float acc0[15], acc1[15];
    #pragma unroll
    for (int n = 0; n < 15; ++n) { acc0[n] = 0.f; acc1[n] = 0.f; }

    #pragma unroll 2
    for (int cq = 0; cq < 32; ++cq) {
        const float4 wa = wT4[cq * 1024 + o0];         // coalesced
        const float4 wb = wT4[cq * 1024 + o1];
        #pragma unroll
        for (int n = 0; n < 15; ++n) {
            const float4 h4 = hb4[n * 32 + cq];        // vector bcast load
            acc0[n] = fmaf(wa.x, h4.x, fmaf(wa.y, h4.y,
                      fmaf(wa.z, h4.z, fmaf(wa.w, h4.w, acc0[n]))));
            acc1[n] = fmaf(wb.x, h4.x, fmaf(wb.y, h4.y,
                      fmaf(wb.z, h4.z, fmaf(wb.w, h4.w, acc1[n]))));
        }
    }
    float m0 = -INFINITY, m1 = -INFINITY;
    #pragma unroll
    for (int n = 0; n < 15; ++n) { m0 = fmaxf(m0, acc0[n]); m1 = fmaxf(m1, acc1[n]); }
    gout[(size_t)b * 1024 + o0] = m0 + bias3[o0];
    gout[(size_t)b * 1024 + o1] = m1 + bias3[o1];
}

// ---------------------------------------------------------------------------
// FC GEMM (unchanged, R2-validated): C = act(A * W^T + ...)
// ---------------------------------------------------------------------------
template <bool BN_RELU>
__global__ __launch_bounds__(256) void k_fc(
    const float* __restrict__ A, const float* __restrict__ W,
    const float* __restrict__ bias,
    const float* __restrict__ gg, const float* __restrict__ be,
    const float* __restrict__ mm, const float* __restrict__ vv,
    float* __restrict__ C, int K, int Nc)
{
    __shared__ float As[32][33];
    __shared__ float Ws[32][33];

    const int tid = threadIdx.x;
    const int bm = blockIdx.x * 32, bn = blockIdx.y * 32;
    const int ml = (tid >> 4) * 2, nl = (tid & 15) * 2;
    const int row = tid >> 3, kq = (tid & 7) * 4;

    float acc00 = 0.f, acc01 = 0.f, acc10 = 0.f, acc11 = 0.f;

    for (int k0 = 0; k0 < K; k0 += 32) {
        const float4 av = *(const float4*)(A + (size_t)(bm + row) * K + k0 + kq);
        const float4 wv = *(const float4*)(W + (size_t)(bn + row) * K + k0 + kq);
        __syncthreads();
        As[row][kq + 0] = av.x; As[row][kq + 1] = av.y;
        As[row][kq + 2] = av.z; As[row][kq + 3] = av.w;
        Ws[row][kq + 0] = wv.x; Ws[row][kq + 1] = wv.y;
        Ws[row][kq + 2] = wv.z; Ws[row][kq + 3] = wv.w;
        __syncthreads();
        #pragma unroll
        for (int k = 0; k < 32; ++k) {
            const float a0 = As[ml][k], a1 = As[ml + 1][k];
            const float b0 = Ws[nl][k], b1 = Ws[nl + 1][k];
            acc00 = fmaf(a0, b0, acc00); acc01 = fmaf(a0, b1, acc01);
            acc10 = fmaf(a1, b0, acc10); acc11 = fmaf(a1, b1, acc11);
        }
    }

    const int n0 = bn + nl, n1 = n0 + 1;
    float v00, v01, v10, v11;
    if (BN_RELU) {
        const float s0 = gg[n0] * rsqrtf(vv[n0] + EPS);
        const float s1 = gg[n1] * rsqrtf(vv[n1] + EPS);
        const float c0 = s0 * (bias[n0] - mm[n0]) + be[n0];
        const float c1 = s1 * (bias[n1] - mm[n1]) + be[n1];
        v00 = fmaxf(fmaf(s0, acc00, c0), 0.f); v01 = fmaxf(fmaf(s1, acc01, c1), 0.f);
        v10 = fmaxf(fmaf(s0, acc10, c0), 0.f); v11 = fmaxf(fmaf(s1, acc11, c1), 0.f);
    } else {
        v00 = acc00 + bias[n0]; v01 = acc01 + bias[n1];
        v10 = acc10 + bias[n0]; v11 = acc11 + bias[n1];
    }
    float* cr0 = C + (size_t)(bm + ml) * Nc + n0;
    cr0[0] = v00; cr0[1] = v01;
    float* cr1 = C + (size_t)(bm + ml + 1) * Nc + n0;
    cr1[0] = v10; cr1[1] = v11;
}

// ---------------------------------------------------------------------------
extern "C" void kernel_launch(void* const* d_in, const int* in_sizes, int n_in,
                              void* d_out, int out_size, void* d_ws, size_t ws_size,
                              hipStream_t stream)
{
    const float* pts     = (const float*)d_in[0];
    // d_in[1] = label (unused)
    const float* info    = (const float*)d_in[2];
    const float* w_info  = (const float*)d_in[3];
    const float* b_info  = (const float*)d_in[4];
    const float* g_info  = (const float*)d_in[5];
    const float* be_info = (const float*)d_in[6];
    const float* m_info  = (const float*)d_in[7];
    const float* v_info  = (const float*)d_in[8];
    const float* w2      = (const float*)d_in[9];
    const float* b2      = (const float*)d_in[10];
    const float* g2      = (const float*)d_in[11];
    const float* be2     = (const float*)d_in[12];
    const float* m2      = (const float*)d_in[13];
    const float* v2      = (const float*)d_in[14];
    const float* w3      = (const float*)d_in[15];
    const float* b3      = (const float*)d_in[16];
    const float* g3      = (const float*)d_in[17];
    const float* be3     = (const float*)d_in[18];
    const float* m3      = (const float*)d_in[19];
    const float* v3      = (const float*)d_in[20];
    const float* wf1     = (const float*)d_in[21];
    const float* bf1     = (const float*)d_in[22];
    const float* gf1     = (const float*)d_in[23];
    const float* bef1    = (const float*)d_in[24];
    const float* mf1     = (const float*)d_in[25];
    const float* vf1     = (const float*)d_in[26];
    const float* wf2     = (const float*)d_in[27];
    const float* bf2     = (const float*)d_in[28];
    const float* gf2     = (const float*)d_in[29];
    const float* bef2    = (const float*)d_in[30];
    const float* mf2     = (const float*)d_in[31];
    const float* vf2     = (const float*)d_in[32];
    const float* wf3     = (const float*)d_in[33];
    const float* bf3     = (const float*)d_in[34];

    float* ws  = (float*)d_ws;
    float*  h2    = ws;                                        // 491520 floats
    float*  g     = ws + 491520;                               // 262144
    float*  f1    = ws + 491520 + 262144;                      // 131072
    float4* wT4   = (float4*)(ws + 491520 + 262144 + 131072);  // 32768 float4
    float*  bias3 = ws + 491520 + 262144 + 131072 + 131072;    // 1024

    float* ret = (float*)d_out;            // [256, 800]
    float* f2  = ret + 256 * 800;          // [256, 256]

    k_wT<<<128, 256, 0, stream>>>(w3, b3, g3, be3, m3, v3, wT4, bias3);

    k_stage12<<<256, 1024, 0, stream>>>(
        pts, info, w_info, b_info, g_info, be_info, m_info, v_info,
        w2, b2, g2, be2, m2, v2, h2);

    k_stage3max<<<256, 512, 0, stream>>>(h2, wT4, bias3, g);

    k_fc<true><<<dim3(8, 16), 256, 0, stream>>>(
        g, wf1, bf1, gf1, bef1, mf1, vf1, f1, 1024, 512);

    k_fc<true><<<dim3(8, 8), 256, 0, stream>>>(
        f1, wf2, bf2, gf2, bef2, mf2, vf2, f2, 512, 256);

    k_fc<false><<<dim3(8, 25), 256, 0, stream>>>(
        f2, wf3, bf3, nullptr, nullptr, nullptr, nullptr, ret, 256, 800);
}

// Round 7
// 152.277 us; speedup vs baseline: 1.4774x; 1.1299x over previous
//
#include <hip/hip_runtime.h>
#include <math.h>

#define EPS 1e-5f

// ---- DPP quad-reduction helpers (VALU-only cross-lane max within quads) ----
__device__ __forceinline__ float dpp_xor1_max(float x) {
    int xi = __float_as_int(x);
    int yi = __builtin_amdgcn_update_dpp(xi, xi, 0xB1, 0xF, 0xF, true); // quad_perm [1,0,3,2]
    return fmaxf(x, __int_as_float(yi));
}
__device__ __forceinline__ float dpp_xor2_max(float x) {
    int xi = __float_as_int(x);
    int yi = __builtin_amdgcn_update_dpp(xi, xi, 0x4E, 0xF, 0xF, true); // quad_perm [2,3,0,1]
    return fmaxf(x, __int_as_float(yi));
}

// ---------------------------------------------------------------------------
// Pre-pass (130 blocks):
//  blocks 0..127 : wT4[cq][o] = a3*w3 quad-major + bias3   (conv3 fold)
//  block  128    : w2q[cq][o2][4] = a2*w2 + bias2          (conv2 fold)
//  block  129    : cTab4[o]=(a*w0,a*w1,a*w2,0), qTab4[o]=(a*(w3-w0),...,t)
// ---------------------------------------------------------------------------
__global__ __launch_bounds__(256) void k_pre(
    const float* __restrict__ w3, const float* __restrict__ b3,
    const float* __restrict__ g3, const float* __restrict__ be3,
    const float* __restrict__ m3, const float* __restrict__ v3,
    const float* __restrict__ w2, const float* __restrict__ b2,
    const float* __restrict__ g2, const float* __restrict__ be2,
    const float* __restrict__ m2, const float* __restrict__ v2,
    const float* __restrict__ w_info, const float* __restrict__ b_info,
    const float* __restrict__ g_info, const float* __restrict__ be_info,
    const float* __restrict__ m_info, const float* __restrict__ v_info,
    float4* __restrict__ wT4, float* __restrict__ bias3,
    float4* __restrict__ w2q, float* __restrict__ bias2,
    float4* __restrict__ cTab4, float4* __restrict__ qTab4)
{
    const int blk = blockIdx.x, tid = threadIdx.x;
    if (blk < 128) {
        const int idx = blk * 256 + tid;      // 0..32767
        const int o  = idx & 1023;
        const int cq = idx >> 10;
        const float a3 = g3[o] * rsqrtf(v3[o] + EPS);
        const float4 w = *(const float4*)(w3 + (size_t)o * 128 + cq * 4);
        wT4[cq * 1024 + o] = make_float4(a3 * w.x, a3 * w.y, a3 * w.z, a3 * w.w);
        if (cq == 0) bias3[o] = a3 * (b3[o] - m3[o]) + be3[o];
    } else if (blk == 128) {
        for (int idx = tid; idx < 2048; idx += 256) {
            const int o2 = idx & 127, cq = idx >> 7;
            const float a2 = g2[o2] * rsqrtf(v2[o2] + EPS);
            const float4 w = *(const float4*)(w2 + (size_t)o2 * 64 + cq * 4);
            w2q[cq * 128 + o2] = make_float4(a2 * w.x, a2 * w.y, a2 * w.z, a2 * w.w);
        }
        if (tid < 128) {
            const float a2 = g2[tid] * rsqrtf(v2[tid] + EPS);
            bias2[tid] = a2 * (b2[tid] - m2[tid]) + be2[tid];
        }
    } else {
        if (tid < 64) {
            const int o = tid;
            const float w0 = w_info[o*6+0], w1 = w_info[o*6+1], w2c = w_info[o*6+2];
            const float w3c = w_info[o*6+3], w4 = w_info[o*6+4], w5 = w_info[o*6+5];
            const float a = g_info[o] * rsqrtf(v_info[o] + EPS);
            cTab4[o] = make_float4(a*w0, a*w1, a*w2c, 0.f);
            qTab4[o] = make_float4(a*(w3c-w0), a*(w4-w1), a*(w5-w2c),
                                   a*(b_info[o]-m_info[o]) + be_info[o]);
        }
    }
}

// ---------------------------------------------------------------------------
// k_edge: edge-conv (6->64) + BN + ReLU + max over the block's k-half.
// Block = (b, half): stage 260 k-rows (46.8KB) coalesced into LDS, then
// wave = n (15 of 16), LANE = K (no broadcast!): each lane reads its own
// d-triplet (conflict-free: 45 mod 32 coprime, lane+32 aliases = free 2-way),
// 16-o tiles with coeffs in SGPRs (uniform K$-resident 2KB table).
// Reduction: 2 DPP quad-steps + per-wave part[16][17] LDS round.
// Writes gpart[b][half][n][o]; conv2 deferred to k_mid.
// ---------------------------------------------------------------------------
__global__ __launch_bounds__(1024, 4) void k_edge(
    const float* __restrict__ pts,        // [256,15,3]
    const float* __restrict__ info,       // [256,520,15,3]
    const float4* __restrict__ cTab4,     // [64]
    const float4* __restrict__ qTab4,     // [64]
    float* __restrict__ gpart)            // [256][2][15][64]
{
    __shared__ float ds[11700];           // [260][15][3]
    __shared__ float part[15][16][17];    // per-wave reduce scratch (pad 17)

    const int tid  = threadIdx.x;
    const int b    = blockIdx.x >> 1;
    const int half = blockIdx.x & 1;

    { // coalesced staging of this half's 260 k-rows
        const float4* src = (const float4*)(info + (size_t)b * 23400 + half * 11700);
        float4* dst = (float4*)ds;
        for (int i = tid; i < 2925; i += 1024) dst[i] = src[i];
    }
    __syncthreads();

    const int wave = tid >> 6, lane = tid & 63;
    if (wave < 15) {
        const int n = wave;
        const float x0 = pts[b*45 + n*3 + 0];
        const float x1 = pts[b*45 + n*3 + 1];
        const float x2 = pts[b*45 + n*3 + 2];
        float* gp = gpart + ((size_t)(b*2 + half)*15 + n) * 64;

        for (int t = 0; t < 4; ++t) {     // o-tiles of 16
            float c0[16], c1[16], c2[16], bias[16];
            #pragma unroll
            for (int j = 0; j < 16; ++j) {
                const int o = t*16 + j;
                const float4 qv = qTab4[o];   // uniform -> s_load
                bias[j] = fmaf(qv.x, x0, fmaf(qv.y, x1, fmaf(qv.z, x2, qv.w)));
                const float4 cv = cTab4[o];   // uniform -> SGPRs
                c0[j] = cv.x; c1[j] = cv.y; c2[j] = cv.z;
            }
            float acc[16];
            #pragma unroll
            for (int j = 0; j < 16; ++j) acc[j] = 0.f;   // relu floor

            for (int kk = lane; kk < 260; kk += 64) {
                const float* p = ds + kk*45 + n*3;       // per-lane LDS read
                const float d0 = p[0], d1 = p[1], d2 = p[2];
                #pragma unroll
                for (int j = 0; j < 16; ++j)
                    acc[j] = fmaxf(acc[j],
                        fmaf(c0[j], d0, fmaf(c1[j], d1, fmaf(c2[j], d2, bias[j]))));
            }
            // quad pre-reduce (all lanes of a quad hold quad-max, VALU only)
            #pragma unroll
            for (int j = 0; j < 16; ++j) {
                acc[j] = dpp_xor1_max(acc[j]);
                acc[j] = dpp_xor2_max(acc[j]);
            }
            // stage A: 4 slots per lane, static reg index via cndmask select
            const int q4 = lane >> 2, r4 = lane & 3;
            #pragma unroll
            for (int i = 0; i < 4; ++i) {
                float v = acc[4*i];
                v = (r4 == 1) ? acc[4*i+1] : v;
                v = (r4 == 2) ? acc[4*i+2] : v;
                v = (r4 == 3) ? acc[4*i+3] : v;
                part[n][4*i + r4][q4] = v;
            }
            // same-wave cross-lane LDS: pin order + drain (rule #18)
            __builtin_amdgcn_sched_barrier(0);
            asm volatile("s_waitcnt lgkmcnt(0)" ::: "memory");
            __builtin_amdgcn_sched_barrier(0);
            // stage B: 4 lanes per o gather 4 quads each, then 2 DPP steps
            const int o4 = lane >> 2, j4 = lane & 3;
            float m =          part[n][o4][4*j4 + 0];
            m = fmaxf(m, part[n][o4][4*j4 + 1]);
            m = fmaxf(m, part[n][o4][4*j4 + 2]);
            m = fmaxf(m, part[n][o4][4*j4 + 3]);
            m = dpp_xor1_max(m);
            m = dpp_xor2_max(m);
            if (j4 == 0) gp[t*16 + o4] = m;
            __builtin_amdgcn_sched_barrier(0);
            asm volatile("s_waitcnt lgkmcnt(0)" ::: "memory");
            __builtin_amdgcn_sched_barrier(0);
        }
    }
}

// ---------------------------------------------------------------------------
// k_mid: combine the two k-half maxima -> h1, then conv2 (64->128, BN+ReLU
// folded into w2q/bias2) -> h2 global.  One block per b, 256 thr.
// ---------------------------------------------------------------------------
__global__ __launch_bounds__(256) void k_mid(
    const float* __restrict__ gpart,  // [256][2][15][64]
    const float4* __restrict__ w2q,   // [16][128]
    const float* __restrict__ bias2,  // [128]
    float* __restrict__ h2out)        // [256,15,128]
{
    __shared__ float h1s[960];        // [15][64]
    const int tid = threadIdx.x;
    const int b = blockIdx.x;

    const float* gp = gpart + (size_t)b * 1920;
    for (int i = tid; i < 960; i += 256)
        h1s[i] = fmaxf(gp[i], gp[960 + i]);
    __syncthreads();

    for (int idx = tid; idx < 1920; idx += 256) {
        const int o2 = idx & 127, n = idx >> 7;   // n uniform per wave
        float acc = 0.f;
        #pragma unroll
        for (int cq = 0; cq < 16; ++cq) {
            const float4 h4 = *(const float4*)(&h1s[n*64 + cq*4]); // LDS bcast
            const float4 w4 = w2q[cq*128 + o2];                    // coalesced
            acc = fmaf(w4.x, h4.x, fmaf(w4.y, h4.y,
                  fmaf(w4.z, h4.z, fmaf(w4.w, h4.w, acc))));
        }
        h2out[(size_t)b*1920 + n*128 + o2] = fmaxf(acc + bias2[o2], 0.f);
    }
}

// ---------------------------------------------------------------------------
// k_s3: conv3 (128->1024, scale folded in wT4) + global max over N=15.
// One block per b, 512 thr; thread handles o and o+512.  h-row loads forced
// onto the vector path via opaque-zero VGPR index (R5 lesson).
// ---------------------------------------------------------------------------
__global__ __launch_bounds__(512) void k_s3(
    const float* __restrict__ h2,     // [256,15,128]
    const float4* __restrict__ wT4,   // [32][1024]
    const float* __restrict__ bias3,  // [1024]
    float* __restrict__ gout)         // [256,1024]
{
    const int tid = threadIdx.x;
    const int b   = blockIdx.x;
    const int o0  = tid, o1 = tid + 512;

    int kz = 0;
    asm volatile("" : "+v"(kz));                       // opaque 0 in a VGPR
    const float4* hb4 = (const float4*)(h2 + (size_t)b * 1920) + kz;

    float acc0[15], acc1[15];
    #pragma unroll
    for (int n = 0; n < 15; ++n) { acc0[n] = 0.f; acc1[n] = 0.f; }

    #pragma unroll 2
    for (int cq = 0; cq < 32; ++cq) {
        const float4 wa = wT4[cq * 1024 + o0];
        const float4 wb = wT4[cq * 1024 + o1];
        #pragma unroll
        for (int n = 0; n < 15; ++n) {
            const float4 h4 = hb4[n * 32 + cq];        // vector bcast load
            acc0[n] = fmaf(wa.x, h4.x, fmaf(wa.y, h4.y,
                      fmaf(wa.z, h4.z, fmaf(wa.w, h4.w, acc0[n]))));
            acc1[n] = fmaf(wb.x, h4.x, fmaf(wb.y, h4.y,
                      fmaf(wb.z, h4.z, fmaf(wb.w, h4.w, acc1[n]))));
        }
    }
    float m0 = -INFINITY, m1 = -INFINITY;
    #pragma unroll
    for (int n = 0; n < 15; ++n) { m0 = fmaxf(m0, acc0[n]); m1 = fmaxf(m1, acc1[n]); }
    gout[(size_t)b * 1024 + o0] = m0 + bias3[o0];
    gout[(size_t)b * 1024 + o1] = m1 + bias3[o1];
}

// ---------------------------------------------------------------------------
// FC GEMM: pad 36 (16B-aligned rows) + float4 LDS micro-kernel.
// ---------------------------------------------------------------------------
template <bool BN_RELU>
__global__ __launch_bounds__(256) void k_fc(
    const float* __restrict__ A, const float* __restrict__ W,
    const float* __restrict__ bias,
    const float* __restrict__ gg, const float* __restrict__ be,
    const float* __restrict__ mm, const float* __restrict__ vv,
    float* __restrict__ C, int K, int Nc)
{
    __shared__ float As[32][36];
    __shared__ float Ws[32][36];

    const int tid = threadIdx.x;
    const int bm = blockIdx.x * 32, bn = blockIdx.y * 32;
    const int ml = (tid >> 4) * 2, nl = (tid & 15) * 2;
    const int row = tid >> 3, kq = (tid & 7) * 4;

    float acc00 = 0.f, acc01 = 0.f, acc10 = 0.f, acc11 = 0.f;

    for (int k0 = 0; k0 < K; k0 += 32) {
        const float4 av = *(const float4*)(A + (size_t)(bm + row) * K + k0 + kq);
        const float4 wv = *(const float4*)(W + (size_t)(bn + row) * K + k0 + kq);
        __syncthreads();
        *(float4*)(&As[row][kq]) = av;
        *(float4*)(&Ws[row][kq]) = wv;
        __syncthreads();
        const float4* a0p = (const float4*)(&As[ml][0]);
        const float4* a1p = (const float4*)(&As[ml + 1][0]);
        const float4* b0p = (const float4*)(&Ws[nl][0]);
        const float4* b1p = (const float4*)(&Ws[nl + 1][0]);
        #pragma unroll
        for (int q = 0; q < 8; ++q) {
            const float4 a0 = a0p[q], a1 = a1p[q], b0 = b0p[q], b1 = b1p[q];
            acc00 = fmaf(a0.x, b0.x, fmaf(a0.y, b0.y, fmaf(a0.z, b0.z, fmaf(a0.w, b0.w, acc00))));
            acc01 = fmaf(a0.x, b1.x, fmaf(a0.y, b1.y, fmaf(a0.z, b1.z, fmaf(a0.w, b1.w, acc01))));
            acc10 = fmaf(a1.x, b0.x, fmaf(a1.y, b0.y, fmaf(a1.z, b0.z, fmaf(a1.w, b0.w, acc10))));
            acc11 = fmaf(a1.x, b1.x, fmaf(a1.y, b1.y, fmaf(a1.z, b1.z, fmaf(a1.w, b1.w, acc11))));
        }
    }

    const int n0 = bn + nl, n1 = n0 + 1;
    float v00, v01, v10, v11;
    if (BN_RELU) {
        const float s0 = gg[n0] * rsqrtf(vv[n0] + EPS);
        const float s1 = gg[n1] * rsqrtf(vv[n1] + EPS);
        const float c0 = s0 * (bias[n0] - mm[n0]) + be[n0];
        const float c1 = s1 * (bias[n1] - mm[n1]) + be[n1];
        v00 = fmaxf(fmaf(s0, acc00, c0), 0.f); v01 = fmaxf(fmaf(s1, acc01, c1), 0.f);
        v10 = fmaxf(fmaf(s0, acc10, c0), 0.f); v11 = fmaxf(fmaf(s1, acc11, c1), 0.f);
    } else {
        v00 = acc00 + bias[n0]; v01 = acc01 + bias[n1];
        v10 = acc10 + bias[n0]; v11 = acc11 + bias[n1];
    }
    float* cr0 = C + (size_t)(bm + ml) * Nc + n0;
    cr0[0] = v00; cr0[1] = v01;
    float* cr1 = C + (size_t)(bm + ml + 1) * Nc + n0;
    cr1[0] = v10; cr1[1] = v11;
}

// ---------------------------------------------------------------------------
extern "C" void kernel_launch(void* const* d_in, const int* in_sizes, int n_in,
                              void* d_out, int out_size, void* d_ws, size_t ws_size,
                              hipStream_t stream)
{
    const float* pts     = (const float*)d_in[0];
    const float* info    = (const float*)d_in[2];
    const float* w_info  = (const float*)d_in[3];
    const float* b_info  = (const float*)d_in[4];
    const float* g_info  = (const float*)d_in[5];
    const float* be_info = (const float*)d_in[6];
    const float* m_info  = (const float*)d_in[7];
    const float* v_info  = (const float*)d_in[8];
    const float* w2      = (const float*)d_in[9];
    const float* b2      = (const float*)d_in[10];
    const float* g2      = (const float*)d_in[11];
    const float* be2     = (const float*)d_in[12];
    const float* m2      = (const float*)d_in[13];
    const float* v2      = (const float*)d_in[14];
    const float* w3      = (const float*)d_in[15];
    const float* b3      = (const float*)d_in[16];
    const float* g3      = (const float*)d_in[17];
    const float* be3     = (const float*)d_in[18];
    const float* m3      = (const float*)d_in[19];
    const float* v3      = (const float*)d_in[20];
    const float* wf1     = (const float*)d_in[21];
    const float* bf1     = (const float*)d_in[22];
    const float* gf1     = (const float*)d_in[23];
    const float* bef1    = (const float*)d_in[24];
    const float* mf1     = (const float*)d_in[25];
    const float* vf1     = (const float*)d_in[26];
    const float* wf2     = (const float*)d_in[27];
    const float* bf2     = (const float*)d_in[28];
    const float* gf2     = (const float*)d_in[29];
    const float* bef2    = (const float*)d_in[30];
    const float* mf2     = (const float*)d_in[31];
    const float* vf2     = (const float*)d_in[32];
    const float* wf3     = (const float*)d_in[33];
    const float* bf3     = (const float*)d_in[34];

    float* ws = (float*)d_ws;
    // layout (floats):
    float*  h2    = ws;                    // 491520
    float*  A     = ws + 491520;           // 491520 shared region:
    float*  gpart = A;                     //   gpart [256][2][15][64] (dead after k_mid)
    float*  g     = A;                     //   then g [256][1024]
    float*  f1    = A + 262144;            //   and f1 [256][512]
    float4* wT4   = (float4*)(ws + 983040);           // 131072 floats
    float4* w2q   = (float4*)(ws + 983040 + 131072);  // 8192 floats
    float*  bias3 = ws + 983040 + 131072 + 8192;      // 1024
    float*  bias2 = bias3 + 1024;                     // 128
    float4* cTab4 = (float4*)(bias2 + 128);           // 256 floats
    float4* qTab4 = (float4*)(bias2 + 128 + 256);     // 256 floats

    float* ret = (float*)d_out;            // [256, 800]
    float* f2  = ret + 256 * 800;          // [256, 256]

    k_pre<<<130, 256, 0, stream>>>(
        w3, b3, g3, be3, m3, v3,
        w2, b2, g2, be2, m2, v2,
        w_info, b_info, g_info, be_info, m_info, v_info,
        wT4, bias3, w2q, bias2, cTab4, qTab4);

    k_edge<<<512, 1024, 0, stream>>>(pts, info, cTab4, qTab4, gpart);

    k_mid<<<256, 256, 0, stream>>>(gpart, w2q, bias2, h2);

    k_s3<<<256, 512, 0, stream>>>(h2, wT4, bias3, g);

    k_fc<true><<<dim3(8, 16), 256, 0, stream>>>(
        g, wf1, bf1, gf1, bef1, mf1, vf1, f1, 1024, 512);

    k_fc<true><<<dim3(8, 8), 256, 0, stream>>>(
        f1, wf2, bf2, gf2, bef2, mf2, vf2, f2, 512, 256);

    k_fc<false><<<dim3(8, 25), 256, 0, stream>>>(
        f2, wf3, bf3, nullptr, nullptr, nullptr, nullptr, ret, 256, 800);
}

// Round 8
// 149.158 us; speedup vs baseline: 1.5083x; 1.0209x over previous
//
#include <hip/hip_runtime.h>
#include <math.h>

#define EPS 1e-5f

// ---- DPP quad-reduction helpers (VALU-only cross-lane max within quads) ----
__device__ __forceinline__ float dpp_xor1_max(float x) {
    int xi = __float_as_int(x);
    int yi = __builtin_amdgcn_update_dpp(xi, xi, 0xB1, 0xF, 0xF, true); // quad_perm [1,0,3,2]
    return fmaxf(x, __int_as_float(yi));
}
__device__ __forceinline__ float dpp_xor2_max(float x) {
    int xi = __float_as_int(x);
    int yi = __builtin_amdgcn_update_dpp(xi, xi, 0x4E, 0xF, 0xF, true); // quad_perm [2,3,0,1]
    return fmaxf(x, __int_as_float(yi));
}

// ---------------------------------------------------------------------------
// Pre-pass (130 blocks):
//  blocks 0..127 : wT4[cq][o] = a3*w3 quad-major + bias3   (conv3 fold)
//  block  128    : w2q[cq][o2][4] = a2*w2 + bias2          (conv2 fold)
//  block  129    : cTab4/qTab4 (edge fold) + sf1/cf1 (f1 BN fold) + sf2/cf2
// ---------------------------------------------------------------------------
__global__ __launch_bounds__(256) void k_pre(
    const float* __restrict__ w3, const float* __restrict__ b3,
    const float* __restrict__ g3, const float* __restrict__ be3,
    const float* __restrict__ m3, const float* __restrict__ v3,
    const float* __restrict__ w2, const float* __restrict__ b2,
    const float* __restrict__ g2, const float* __restrict__ be2,
    const float* __restrict__ m2, const float* __restrict__ v2,
    const float* __restrict__ w_info, const float* __restrict__ b_info,
    const float* __restrict__ g_info, const float* __restrict__ be_info,
    const float* __restrict__ m_info, const float* __restrict__ v_info,
    const float* __restrict__ bf1, const float* __restrict__ gf1,
    const float* __restrict__ bef1, const float* __restrict__ mf1,
    const float* __restrict__ vf1,
    const float* __restrict__ bf2, const float* __restrict__ gf2,
    const float* __restrict__ bef2, const float* __restrict__ mf2,
    const float* __restrict__ vf2,
    float4* __restrict__ wT4, float* __restrict__ bias3,
    float4* __restrict__ w2q, float* __restrict__ bias2,
    float4* __restrict__ cTab4, float4* __restrict__ qTab4,
    float* __restrict__ sf1, float* __restrict__ cf1,
    float* __restrict__ sf2, float* __restrict__ cf2)
{
    const int blk = blockIdx.x, tid = threadIdx.x;
    if (blk < 128) {
        const int idx = blk * 256 + tid;      // 0..32767
        const int o  = idx & 1023;
        const int cq = idx >> 10;
        const float a3 = g3[o] * rsqrtf(v3[o] + EPS);
        const float4 w = *(const float4*)(w3 + (size_t)o * 128 + cq * 4);
        wT4[cq * 1024 + o] = make_float4(a3 * w.x, a3 * w.y, a3 * w.z, a3 * w.w);
        if (cq == 0) bias3[o] = a3 * (b3[o] - m3[o]) + be3[o];
    } else if (blk == 128) {
        for (int idx = tid; idx < 2048; idx += 256) {
            const int o2 = idx & 127, cq = idx >> 7;
            const float a2 = g2[o2] * rsqrtf(v2[o2] + EPS);
            const float4 w = *(const float4*)(w2 + (size_t)o2 * 64 + cq * 4);
            w2q[cq * 128 + o2] = make_float4(a2 * w.x, a2 * w.y, a2 * w.z, a2 * w.w);
        }
        if (tid < 128) {
            const float a2 = g2[tid] * rsqrtf(v2[tid] + EPS);
            bias2[tid] = a2 * (b2[tid] - m2[tid]) + be2[tid];
        }
    } else {
        if (tid < 64) {
            const int o = tid;
            const float w0 = w_info[o*6+0], w1 = w_info[o*6+1], w2c = w_info[o*6+2];
            const float w3c = w_info[o*6+3], w4 = w_info[o*6+4], w5 = w_info[o*6+5];
            const float a = g_info[o] * rsqrtf(v_info[o] + EPS);
            cTab4[o] = make_float4(a*w0, a*w1, a*w2c, 0.f);
            qTab4[o] = make_float4(a*(w3c-w0), a*(w4-w1), a*(w5-w2c),
                                   a*(b_info[o]-m_info[o]) + be_info[o]);
        }
        for (int c = tid; c < 512; c += 256) {
            const float s = gf1[c] * rsqrtf(vf1[c] + EPS);
            sf1[c] = s;
            cf1[c] = s * (bf1[c] - mf1[c]) + bef1[c];
        }
        {
            const int c = tid;   // 256 threads, 256 channels
            const float s = gf2[c] * rsqrtf(vf2[c] + EPS);
            sf2[c] = s;
            cf2[c] = s * (bf2[c] - mf2[c]) + bef2[c];
        }
    }
}

// ---------------------------------------------------------------------------
// k_edge: edge-conv (6->64) + BN + ReLU + max over the block's k-half.
// (unchanged from R7 — validated; lane = K, coeffs in SGPRs, DPP reduce)
// ---------------------------------------------------------------------------
__global__ __launch_bounds__(1024, 4) void k_edge(
    const float* __restrict__ pts,        // [256,15,3]
    const float* __restrict__ info,       // [256,520,15,3]
    const float4* __restrict__ cTab4,     // [64]
    const float4* __restrict__ qTab4,     // [64]
    float* __restrict__ gpart)            // [256][2][15][64]
{
    __shared__ float ds[11700];           // [260][15][3]
    __shared__ float part[15][16][17];

    const int tid  = threadIdx.x;
    const int b    = blockIdx.x >> 1;
    const int half = blockIdx.x & 1;

    { // coalesced staging of this half's 260 k-rows
        const float4* src = (const float4*)(info + (size_t)b * 23400 + half * 11700);
        float4* dst = (float4*)ds;
        for (int i = tid; i < 2925; i += 1024) dst[i] = src[i];
    }
    __syncthreads();

    const int wave = tid >> 6, lane = tid & 63;
    if (wave < 15) {
        const int n = wave;
        const float x0 = pts[b*45 + n*3 + 0];
        const float x1 = pts[b*45 + n*3 + 1];
        const float x2 = pts[b*45 + n*3 + 2];
        float* gp = gpart + ((size_t)(b*2 + half)*15 + n) * 64;

        for (int t = 0; t < 4; ++t) {     // o-tiles of 16
            float c0[16], c1[16], c2[16], bias[16];
            #pragma unroll
            for (int j = 0; j < 16; ++j) {
                const int o = t*16 + j;
                const float4 qv = qTab4[o];
                bias[j] = fmaf(qv.x, x0, fmaf(qv.y, x1, fmaf(qv.z, x2, qv.w)));
                const float4 cv = cTab4[o];
                c0[j] = cv.x; c1[j] = cv.y; c2[j] = cv.z;
            }
            float acc[16];
            #pragma unroll
            for (int j = 0; j < 16; ++j) acc[j] = 0.f;   // relu floor

            for (int kk = lane; kk < 260; kk += 64) {
                const float* p = ds + kk*45 + n*3;       // per-lane LDS read
                const float d0 = p[0], d1 = p[1], d2 = p[2];
                #pragma unroll
                for (int j = 0; j < 16; ++j)
                    acc[j] = fmaxf(acc[j],
                        fmaf(c0[j], d0, fmaf(c1[j], d1, fmaf(c2[j], d2, bias[j]))));
            }
            #pragma unroll
            for (int j = 0; j < 16; ++j) {
                acc[j] = dpp_xor1_max(acc[j]);
                acc[j] = dpp_xor2_max(acc[j]);
            }
            const int q4 = lane >> 2, r4 = lane & 3;
            #pragma unroll
            for (int i = 0; i < 4; ++i) {
                float v = acc[4*i];
                v = (r4 == 1) ? acc[4*i+1] : v;
                v = (r4 == 2) ? acc[4*i+2] : v;
                v = (r4 == 3) ? acc[4*i+3] : v;
                part[n][4*i + r4][q4] = v;
            }
            __builtin_amdgcn_sched_barrier(0);
            asm volatile("s_waitcnt lgkmcnt(0)" ::: "memory");
            __builtin_amdgcn_sched_barrier(0);
            const int o4 = lane >> 2, j4 = lane & 3;
            float m =          part[n][o4][4*j4 + 0];
            m = fmaxf(m, part[n][o4][4*j4 + 1]);
            m = fmaxf(m, part[n][o4][4*j4 + 2]);
            m = fmaxf(m, part[n][o4][4*j4 + 3]);
            m = dpp_xor1_max(m);
            m = dpp_xor2_max(m);
            if (j4 == 0) gp[t*16 + o4] = m;
            __builtin_amdgcn_sched_barrier(0);
            asm volatile("s_waitcnt lgkmcnt(0)" ::: "memory");
            __builtin_amdgcn_sched_barrier(0);
        }
    }
}

// ---------------------------------------------------------------------------
// k_mid: combine half-maxima -> h1, conv2 (folded) -> h2.  (unchanged)
// ---------------------------------------------------------------------------
__global__ __launch_bounds__(256) void k_mid(
    const float* __restrict__ gpart,  // [256][2][15][64]
    const float4* __restrict__ w2q,   // [16][128]
    const float* __restrict__ bias2,  // [128]
    float* __restrict__ h2out)        // [256,15,128]
{
    __shared__ float h1s[960];        // [15][64]
    const int tid = threadIdx.x;
    const int b = blockIdx.x;

    const float* gp = gpart + (size_t)b * 1920;
    for (int i = tid; i < 960; i += 256)
        h1s[i] = fmaxf(gp[i], gp[960 + i]);
    __syncthreads();

    for (int idx = tid; idx < 1920; idx += 256) {
        const int o2 = idx & 127, n = idx >> 7;
        float acc = 0.f;
        #pragma unroll
        for (int cq = 0; cq < 16; ++cq) {
            const float4 h4 = *(const float4*)(&h1s[n*64 + cq*4]);
            const float4 w4 = w2q[cq*128 + o2];
            acc = fmaf(w4.x, h4.x, fmaf(w4.y, h4.y,
                  fmaf(w4.z, h4.z, fmaf(w4.w, h4.w, acc))));
        }
        h2out[(size_t)b*1920 + n*128 + o2] = fmaxf(acc + bias2[o2], 0.f);
    }
}

// ---------------------------------------------------------------------------
// k_s3: conv3 + global max.  NOW 1024 blocks (b, oq), 256 thr, ONE o/thread.
// R7 failure was occupancy (1 blk/CU, 2 waves/SIMD, latency-bound at 24%
// VALU); this gives 4 blk/CU, 4 waves/SIMD.  blk&255 = b keeps the 4
// same-b blocks on one XCD.  Vector-path broadcast loads via opaque kz.
// ---------------------------------------------------------------------------
__global__ __launch_bounds__(256) void k_s3(
    const float* __restrict__ h2,     // [256,15,128]
    const float4* __restrict__ wT4,   // [32][1024]
    const float* __restrict__ bias3,  // [1024]
    float* __restrict__ gout)         // [256,1024]
{
    const int tid = threadIdx.x;
    const int b   = blockIdx.x & 255;
    const int oq  = blockIdx.x >> 8;
    const int o   = oq * 256 + tid;

    int kz = 0;
    asm volatile("" : "+v"(kz));                       // opaque 0 in a VGPR
    const float4* hb4 = (const float4*)(h2 + (size_t)b * 1920) + kz;

    float acc[15];
    #pragma unroll
    for (int n = 0; n < 15; ++n) acc[n] = 0.f;

    #pragma unroll 2
    for (int cq = 0; cq < 32; ++cq) {
        const float4 w = wT4[cq * 1024 + o];           // coalesced
        #pragma unroll
        for (int n = 0; n < 15; ++n) {
            const float4 h4 = hb4[n * 32 + cq];        // vector bcast load
            acc[n] = fmaf(w.x, h4.x, fmaf(w.y, h4.y,
                     fmaf(w.z, h4.z, fmaf(w.w, h4.w, acc[n]))));
        }
    }
    float m0 = -INFINITY;
    #pragma unroll
    for (int n = 0; n < 15; ++n) m0 = fmaxf(m0, acc[n]);
    gout[(size_t)b * 1024 + o] = m0 + bias3[o];
}

// ---------------------------------------------------------------------------
// k_fc1p: fc1 as split-K=2 raw-partial GEMM.  grid (8,16,2), 32x32 tile.
// P[ks][m][n] = sum over k-slice of g[m][k]*wf1[n][k]  (BN deferred to fc2).
// ---------------------------------------------------------------------------
__global__ __launch_bounds__(256) void k_fc1p(
    const float* __restrict__ A,      // g [256][1024]
    const float* __restrict__ W,      // wf1 [512][1024]
    float* __restrict__ P)            // [2][256][512]
{
    __shared__ float As[32][36];
    __shared__ float Ws[32][36];

    const int tid = threadIdx.x;
    const int bm = blockIdx.x * 32, bn = blockIdx.y * 32;
    const int ks = blockIdx.z;
    const int ml = (tid >> 4) * 2, nl = (tid & 15) * 2;
    const int row = tid >> 3, kq = (tid & 7) * 4;

    float acc00 = 0.f, acc01 = 0.f, acc10 = 0.f, acc11 = 0.f;

    for (int k0 = 0; k0 < 512; k0 += 32) {
        const int ch = ks * 512 + k0 + kq;
        const float4 av = *(const float4*)(A + (size_t)(bm + row) * 1024 + ch);
        const float4 wv = *(const float4*)(W + (size_t)(bn + row) * 1024 + ch);
        __syncthreads();
        *(float4*)(&As[row][kq]) = av;
        *(float4*)(&Ws[row][kq]) = wv;
        __syncthreads();
        const float4* a0p = (const float4*)(&As[ml][0]);
        const float4* a1p = (const float4*)(&As[ml + 1][0]);
        const float4* b0p = (const float4*)(&Ws[nl][0]);
        const float4* b1p = (const float4*)(&Ws[nl + 1][0]);
        #pragma unroll
        for (int q = 0; q < 8; ++q) {
            const float4 a0 = a0p[q], a1 = a1p[q], b0 = b0p[q], b1 = b1p[q];
            acc00 = fmaf(a0.x, b0.x, fmaf(a0.y, b0.y, fmaf(a0.z, b0.z, fmaf(a0.w, b0.w, acc00))));
            acc01 = fmaf(a0.x, b1.x, fmaf(a0.y, b1.y, fmaf(a0.z, b1.z, fmaf(a0.w, b1.w, acc01))));
            acc10 = fmaf(a1.x, b0.x, fmaf(a1.y, b0.y, fmaf(a1.z, b0.z, fmaf(a1.w, b0.w, acc10))));
            acc11 = fmaf(a1.x, b1.x, fmaf(a1.y, b1.y, fmaf(a1.z, b1.z, fmaf(a1.w, b1.w, acc11))));
        }
    }
    float* p0 = P + (size_t)ks * 131072 + (size_t)(bm + ml) * 512 + bn + nl;
    p0[0] = acc00; p0[1] = acc01;
    float* p1 = p0 + 512;
    p1[0] = acc10; p1[1] = acc11;
}

// ---------------------------------------------------------------------------
// k_fc2p: fc2 split-K=2.  A-tile finishes f1 on the fly:
//   f1[m][c] = relu(sf1[c]*(P[0][m][c]+P[1][m][c]) + cf1[c])
// Writes raw partials P2[ks][m][n].
// ---------------------------------------------------------------------------
__global__ __launch_bounds__(256) void k_fc2p(
    const float* __restrict__ fp,     // [2][256][512] fc1 raw partials
    const float* __restrict__ sf1, const float* __restrict__ cf1,
    const float* __restrict__ W,      // wf2 [256][512]
    float* __restrict__ P2)           // [2][256][256]
{
    __shared__ float As[32][36];
    __shared__ float Ws[32][36];

    const int tid = threadIdx.x;
    const int bm = blockIdx.x * 32, bn = blockIdx.y * 32;
    const int ks = blockIdx.z;
    const int ml = (tid >> 4) * 2, nl = (tid & 15) * 2;
    const int row = tid >> 3, kq = (tid & 7) * 4;

    float acc00 = 0.f, acc01 = 0.f, acc10 = 0.f, acc11 = 0.f;

    for (int k0 = 0; k0 < 256; k0 += 32) {
        const int ch = ks * 256 + k0 + kq;
        const float4 p0 = *(const float4*)(fp + (size_t)(bm + row) * 512 + ch);
        const float4 p1 = *(const float4*)(fp + 131072 + (size_t)(bm + row) * 512 + ch);
        const float4 s4 = *(const float4*)(sf1 + ch);
        const float4 c4 = *(const float4*)(cf1 + ch);
        float4 av;
        av.x = fmaxf(fmaf(s4.x, p0.x + p1.x, c4.x), 0.f);
        av.y = fmaxf(fmaf(s4.y, p0.y + p1.y, c4.y), 0.f);
        av.z = fmaxf(fmaf(s4.z, p0.z + p1.z, c4.z), 0.f);
        av.w = fmaxf(fmaf(s4.w, p0.w + p1.w, c4.w), 0.f);
        const float4 wv = *(const float4*)(W + (size_t)(bn + row) * 512 + ch);
        __syncthreads();
        *(float4*)(&As[row][kq]) = av;
        *(float4*)(&Ws[row][kq]) = wv;
        __syncthreads();
        const float4* a0p = (const float4*)(&As[ml][0]);
        const float4* a1p = (const float4*)(&As[ml + 1][0]);
        const float4* b0p = (const float4*)(&Ws[nl][0]);
        const float4* b1p = (const float4*)(&Ws[nl + 1][0]);
        #pragma unroll
        for (int q = 0; q < 8; ++q) {
            const float4 a0 = a0p[q], a1 = a1p[q], b0 = b0p[q], b1 = b1p[q];
            acc00 = fmaf(a0.x, b0.x, fmaf(a0.y, b0.y, fmaf(a0.z, b0.z, fmaf(a0.w, b0.w, acc00))));
            acc01 = fmaf(a0.x, b1.x, fmaf(a0.y, b1.y, fmaf(a0.z, b1.z, fmaf(a0.w, b1.w, acc01))));
            acc10 = fmaf(a1.x, b0.x, fmaf(a1.y, b0.y, fmaf(a1.z, b0.z, fmaf(a1.w, b0.w, acc10))));
            acc11 = fmaf(a1.x, b1.x, fmaf(a1.y, b1.y, fmaf(a1.z, b1.z, fmaf(a1.w, b1.w, acc11))));
        }
    }
    float* q0 = P2 + (size_t)ks * 65536 + (size_t)(bm + ml) * 256 + bn + nl;
    q0[0] = acc00; q0[1] = acc01;
    float* q1 = q0 + 256;
    q1[0] = acc10; q1[1] = acc11;
}

// ---------------------------------------------------------------------------
// k_ep2: f2 = relu(sf2*(P2[0]+P2[1]) + cf2)   (65536 elems)
// ---------------------------------------------------------------------------
__global__ __launch_bounds__(256) void k_ep2(
    const float* __restrict__ P2, const float* __restrict__ sf2,
    const float* __restrict__ cf2, float* __restrict__ f2)
{
    const int i = blockIdx.x * 256 + threadIdx.x;
    const int n = i & 255;
    const float v = P2[i] + P2[65536 + i];
    f2[i] = fmaxf(fmaf(sf2[n], v, cf2[n]), 0.f);
}

// ---------------------------------------------------------------------------
// k_fc: plain FC GEMM (fc3 only now): C = A*W^T + bias
// ---------------------------------------------------------------------------
__global__ __launch_bounds__(256) void k_fc3(
    const float* __restrict__ A, const float* __restrict__ W,
    const float* __restrict__ bias, float* __restrict__ C, int K, int Nc)
{
    __shared__ float As[32][36];
    __shared__ float Ws[32][36];

    const int tid = threadIdx.x;
    const int bm = blockIdx.x * 32, bn = blockIdx.y * 32;
    const int ml = (tid >> 4) * 2, nl = (tid & 15) * 2;
    const int row = tid >> 3, kq = (tid & 7) * 4;

    float acc00 = 0.f, acc01 = 0.f, acc10 = 0.f, acc11 = 0.f;

    for (int k0 = 0; k0 < K; k0 += 32) {
        const float4 av = *(const float4*)(A + (size_t)(bm + row) * K + k0 + kq);
        const float4 wv = *(const float4*)(W + (size_t)(bn + row) * K + k0 + kq);
        __syncthreads();
        *(float4*)(&As[row][kq]) = av;
        *(float4*)(&Ws[row][kq]) = wv;
        __syncthreads();
        const float4* a0p = (const float4*)(&As[ml][0]);
        const float4* a1p = (const float4*)(&As[ml + 1][0]);
        const float4* b0p = (const float4*)(&Ws[nl][0]);
        const float4* b1p = (const float4*)(&Ws[nl + 1][0]);
        #pragma unroll
        for (int q = 0; q < 8; ++q) {
            const float4 a0 = a0p[q], a1 = a1p[q], b0 = b0p[q], b1 = b1p[q];
            acc00 = fmaf(a0.x, b0.x, fmaf(a0.y, b0.y, fmaf(a0.z, b0.z, fmaf(a0.w, b0.w, acc00))));
            acc01 = fmaf(a0.x, b1.x, fmaf(a0.y, b1.y, fmaf(a0.z, b1.z, fmaf(a0.w, b1.w, acc01))));
            acc10 = fmaf(a1.x, b0.x, fmaf(a1.y, b0.y, fmaf(a1.z, b0.z, fmaf(a1.w, b0.w, acc10))));
            acc11 = fmaf(a1.x, b1.x, fmaf(a1.y, b1.y, fmaf(a1.z, b1.z, fmaf(a1.w, b1.w, acc11))));
        }
    }

    const int n0 = bn + nl, n1 = n0 + 1;
    float* cr0 = C + (size_t)(bm + ml) * Nc + n0;
    cr0[0] = acc00 + bias[n0]; cr0[1] = acc01 + bias[n1];
    float* cr1 = C + (size_t)(bm + ml + 1) * Nc + n0;
    cr1[0] = acc10 + bias[n0]; cr1[1] = acc11 + bias[n1];
}

// ---------------------------------------------------------------------------
extern "C" void kernel_launch(void* const* d_in, const int* in_sizes, int n_in,
                              void* d_out, int out_size, void* d_ws, size_t ws_size,
                              hipStream_t stream)
{
    const float* pts     = (const float*)d_in[0];
    const float* info    = (const float*)d_in[2];
    const float* w_info  = (const float*)d_in[3];
    const float* b_info  = (const float*)d_in[4];
    const float* g_info  = (const float*)d_in[5];
    const float* be_info = (const float*)d_in[6];
    const float* m_info  = (const float*)d_in[7];
    const float* v_info  = (const float*)d_in[8];
    const float* w2      = (const float*)d_in[9];
    const float* b2      = (const float*)d_in[10];
    const float* g2      = (const float*)d_in[11];
    const float* be2     = (const float*)d_in[12];
    const float* m2      = (const float*)d_in[13];
    const float* v2      = (const float*)d_in[14];
    const float* w3      = (const float*)d_in[15];
    const float* b3      = (const float*)d_in[16];
    const float* g3      = (const float*)d_in[17];
    const float* be3     = (const float*)d_in[18];
    const float* m3      = (const float*)d_in[19];
    const float* v3      = (const float*)d_in[20];
    const float* wf1     = (const float*)d_in[21];
    const float* bf1     = (const float*)d_in[22];
    const float* gf1     = (const float*)d_in[23];
    const float* bef1    = (const float*)d_in[24];
    const float* mf1     = (const float*)d_in[25];
    const float* vf1     = (const float*)d_in[26];
    const float* wf2     = (const float*)d_in[27];
    const float* bf2     = (const float*)d_in[28];
    const float* gf2     = (const float*)d_in[29];
    const float* bef2    = (const float*)d_in[30];
    const float* mf2     = (const float*)d_in[31];
    const float* vf2     = (const float*)d_in[32];
    const float* wf3     = (const float*)d_in[33];
    const float* bf3     = (const float*)d_in[34];

    float* ws = (float*)d_ws;
    // region 0: [0 .. 491520)  h2 (live k_mid->k_s3), then fc1 partials fp [2][131072]
    float*  h2    = ws;
    float*  fp    = ws;                    // reuse after k_s3
    // region A: [491520 .. 983040)  gpart (edge->mid) then g [262144] (s3->fc1),
    //           P2 at A+262144 [2][65536] (fc2->ep2)
    float*  Areg  = ws + 491520;
    float*  gpart = Areg;
    float*  g     = Areg;
    float*  P2    = Areg + 262144;
    // constants region
    float4* wT4   = (float4*)(ws + 983040);            // 131072 floats
    float4* w2q   = (float4*)(ws + 983040 + 131072);   // 8192
    float*  bias3 = ws + 983040 + 131072 + 8192;       // 1024
    float*  bias2 = bias3 + 1024;                      // 128
    float4* cTab4 = (float4*)(bias2 + 128);            // 256
    float4* qTab4 = (float4*)(bias2 + 128 + 256);      // 256
    float*  sf1   = bias2 + 128 + 256 + 256;           // 512
    float*  cf1   = sf1 + 512;                         // 512
    float*  sf2   = cf1 + 512;                         // 256
    float*  cf2   = sf2 + 256;                         // 256

    float* ret = (float*)d_out;            // [256, 800]
    float* f2  = ret + 256 * 800;          // [256, 256]

    k_pre<<<130, 256, 0, stream>>>(
        w3, b3, g3, be3, m3, v3,
        w2, b2, g2, be2, m2, v2,
        w_info, b_info, g_info, be_info, m_info, v_info,
        bf1, gf1, bef1, mf1, vf1,
        bf2, gf2, bef2, mf2, vf2,
        wT4, bias3, w2q, bias2, cTab4, qTab4, sf1, cf1, sf2, cf2);

    k_edge<<<512, 1024, 0, stream>>>(pts, info, cTab4, qTab4, gpart);

    k_mid<<<256, 256, 0, stream>>>(gpart, w2q, bias2, h2);

    k_s3<<<1024, 256, 0, stream>>>(h2, wT4, bias3, g);

    k_fc1p<<<dim3(8, 16, 2), 256, 0, stream>>>(g, wf1, fp);

    k_fc2p<<<dim3(8, 8, 2), 256, 0, stream>>>(fp, sf1, cf1, wf2, P2);

    k_ep2<<<256, 256, 0, stream>>>(P2, sf2, cf2, f2);

    k_fc3<<<dim3(8, 25), 256, 0, stream>>>(f2, wf3, bf3, ret, 256, 800);
}

// Round 9
// 122.752 us; speedup vs baseline: 1.8327x; 1.2151x over previous
//
#include <hip/hip_runtime.h>
#include <math.h>

#define EPS 1e-5f

typedef __attribute__((ext_vector_type(8))) short short8v;
typedef __attribute__((ext_vector_type(4))) float f32x4;

// ---- bf16 split helpers (RNE) ----
__device__ __forceinline__ unsigned short bf16r(float x) {
    unsigned u = __float_as_uint(x);
    return (unsigned short)((u + 0x7FFFu + ((u >> 16) & 1u)) >> 16);
}
__device__ __forceinline__ float bf2f(unsigned short h) {
    return __uint_as_float(((unsigned)h) << 16);
}

// ---- DPP quad-reduction helpers ----
__device__ __forceinline__ float dpp_xor1_max(float x) {
    int xi = __float_as_int(x);
    int yi = __builtin_amdgcn_update_dpp(xi, xi, 0xB1, 0xF, 0xF, true);
    return fmaxf(x, __int_as_float(yi));
}
__device__ __forceinline__ float dpp_xor2_max(float x) {
    int xi = __float_as_int(x);
    int yi = __builtin_amdgcn_update_dpp(xi, xi, 0x4E, 0xF, 0xF, true);
    return fmaxf(x, __int_as_float(yi));
}

// ---------------------------------------------------------------------------
// k_pre (66 blocks):
//  blocks 0..63 : Bpack hi/lo = bf16-split of a3*w3 in MFMA B-layout
//                 [kt 0..3][nt 0..63][lane 0..63][j 0..7]
//                 value = a3[o]*w3[o][k], o = nt*16+(lane&15), k = kt*32+(lane>>4)*8+j
//  block  64    : w2q (conv2 fold) + bias2
//  block  65    : cTab4/qTab4 (edge fold) + sf1/cf1 + sf2/cf2 + bias3
// ---------------------------------------------------------------------------
__global__ __launch_bounds__(256) void k_pre(
    const float* __restrict__ w3, const float* __restrict__ b3,
    const float* __restrict__ g3, const float* __restrict__ be3,
    const float* __restrict__ m3, const float* __restrict__ v3,
    const float* __restrict__ w2, const float* __restrict__ b2,
    const float* __restrict__ g2, const float* __restrict__ be2,
    const float* __restrict__ m2, const float* __restrict__ v2,
    const float* __restrict__ w_info, const float* __restrict__ b_info,
    const float* __restrict__ g_info, const float* __restrict__ be_info,
    const float* __restrict__ m_info, const float* __restrict__ v_info,
    const float* __restrict__ bf1, const float* __restrict__ gf1,
    const float* __restrict__ bef1, const float* __restrict__ mf1,
    const float* __restrict__ vf1,
    const float* __restrict__ bf2, const float* __restrict__ gf2,
    const float* __restrict__ bef2, const float* __restrict__ mf2,
    const float* __restrict__ vf2,
    unsigned short* __restrict__ Bh, unsigned short* __restrict__ Bl,
    float* __restrict__ bias3,
    float4* __restrict__ w2q, float* __restrict__ bias2,
    float4* __restrict__ cTab4, float4* __restrict__ qTab4,
    float* __restrict__ sf1, float* __restrict__ cf1,
    float* __restrict__ sf2, float* __restrict__ cf2)
{
    const int blk = blockIdx.x, tid = threadIdx.x;
    if (blk < 64) {
        const int t = blk * 256 + tid;        // 0..16383 -> (kt,nt,lane)
        const int kt = t >> 12;
        const int nt = (t >> 6) & 63;
        const int lane = t & 63;
        const int o  = nt * 16 + (lane & 15);
        const int kb = kt * 32 + ((lane >> 4) << 3);
        const float a3 = g3[o] * rsqrtf(v3[o] + EPS);
        unsigned short hi[8], lo[8];
        #pragma unroll
        for (int j = 0; j < 8; ++j) {
            const float wv = a3 * w3[(size_t)o * 128 + kb + j];
            hi[j] = bf16r(wv);
            lo[j] = bf16r(wv - bf2f(hi[j]));
        }
        #pragma unroll
        for (int j = 0; j < 8; ++j) {
            Bh[(size_t)t * 8 + j] = hi[j];
            Bl[(size_t)t * 8 + j] = lo[j];
        }
    } else if (blk == 64) {
        for (int idx = tid; idx < 2048; idx += 256) {
            const int o2 = idx & 127, cq = idx >> 7;
            const float a2 = g2[o2] * rsqrtf(v2[o2] + EPS);
            const float4 w = *(const float4*)(w2 + (size_t)o2 * 64 + cq * 4);
            w2q[cq * 128 + o2] = make_float4(a2 * w.x, a2 * w.y, a2 * w.z, a2 * w.w);
        }
        if (tid < 128) {
            const float a2 = g2[tid] * rsqrtf(v2[tid] + EPS);
            bias2[tid] = a2 * (b2[tid] - m2[tid]) + be2[tid];
        }
    } else {
        if (tid < 64) {
            const int o = tid;
            const float w0 = w_info[o*6+0], w1 = w_info[o*6+1], w2c = w_info[o*6+2];
            const float w3c = w_info[o*6+3], w4 = w_info[o*6+4], w5 = w_info[o*6+5];
            const float a = g_info[o] * rsqrtf(v_info[o] + EPS);
            cTab4[o] = make_float4(a*w0, a*w1, a*w2c, 0.f);
            qTab4[o] = make_float4(a*(w3c-w0), a*(w4-w1), a*(w5-w2c),
                                   a*(b_info[o]-m_info[o]) + be_info[o]);
        }
        for (int c = tid; c < 1024; c += 256) {
            const float a3 = g3[c] * rsqrtf(v3[c] + EPS);
            bias3[c] = a3 * (b3[c] - m3[c]) + be3[c];
        }
        for (int c = tid; c < 512; c += 256) {
            const float s = gf1[c] * rsqrtf(vf1[c] + EPS);
            sf1[c] = s;
            cf1[c] = s * (bf1[c] - mf1[c]) + bef1[c];
        }
        {
            const int c = tid;
            const float s = gf2[c] * rsqrtf(vf2[c] + EPS);
            sf2[c] = s;
            cf2[c] = s * (bf2[c] - mf2[c]) + bef2[c];
        }
    }
}

// ---------------------------------------------------------------------------
// k_edge: edge-conv (6->64) + BN + ReLU + max over k-half.  (unchanged R7)
// ---------------------------------------------------------------------------
__global__ __launch_bounds__(1024, 4) void k_edge(
    const float* __restrict__ pts,
    const float* __restrict__ info,
    const float4* __restrict__ cTab4,
    const float4* __restrict__ qTab4,
    float* __restrict__ gpart)            // [256][2][15][64]
{
    __shared__ float ds[11700];
    __shared__ float part[15][16][17];

    const int tid  = threadIdx.x;
    const int b    = blockIdx.x >> 1;
    const int half = blockIdx.x & 1;

    {
        const float4* src = (const float4*)(info + (size_t)b * 23400 + half * 11700);
        float4* dst = (float4*)ds;
        for (int i = tid; i < 2925; i += 1024) dst[i] = src[i];
    }
    __syncthreads();

    const int wave = tid >> 6, lane = tid & 63;
    if (wave < 15) {
        const int n = wave;
        const float x0 = pts[b*45 + n*3 + 0];
        const float x1 = pts[b*45 + n*3 + 1];
        const float x2 = pts[b*45 + n*3 + 2];
        float* gp = gpart + ((size_t)(b*2 + half)*15 + n) * 64;

        for (int t = 0; t < 4; ++t) {
            float c0[16], c1[16], c2[16], bias[16];
            #pragma unroll
            for (int j = 0; j < 16; ++j) {
                const int o = t*16 + j;
                const float4 qv = qTab4[o];
                bias[j] = fmaf(qv.x, x0, fmaf(qv.y, x1, fmaf(qv.z, x2, qv.w)));
                const float4 cv = cTab4[o];
                c0[j] = cv.x; c1[j] = cv.y; c2[j] = cv.z;
            }
            float acc[16];
            #pragma unroll
            for (int j = 0; j < 16; ++j) acc[j] = 0.f;

            for (int kk = lane; kk < 260; kk += 64) {
                const float* p = ds + kk*45 + n*3;
                const float d0 = p[0], d1 = p[1], d2 = p[2];
                #pragma unroll
                for (int j = 0; j < 16; ++j)
                    acc[j] = fmaxf(acc[j],
                        fmaf(c0[j], d0, fmaf(c1[j], d1, fmaf(c2[j], d2, bias[j]))));
            }
            #pragma unroll
            for (int j = 0; j < 16; ++j) {
                acc[j] = dpp_xor1_max(acc[j]);
                acc[j] = dpp_xor2_max(acc[j]);
            }
            const int q4 = lane >> 2, r4 = lane & 3;
            #pragma unroll
            for (int i = 0; i < 4; ++i) {
                float v = acc[4*i];
                v = (r4 == 1) ? acc[4*i+1] : v;
                v = (r4 == 2) ? acc[4*i+2] : v;
                v = (r4 == 3) ? acc[4*i+3] : v;
                part[n][4*i + r4][q4] = v;
            }
            __builtin_amdgcn_sched_barrier(0);
            asm volatile("s_waitcnt lgkmcnt(0)" ::: "memory");
            __builtin_amdgcn_sched_barrier(0);
            const int o4 = lane >> 2, j4 = lane & 3;
            float m =          part[n][o4][4*j4 + 0];
            m = fmaxf(m, part[n][o4][4*j4 + 1]);
            m = fmaxf(m, part[n][o4][4*j4 + 2]);
            m = fmaxf(m, part[n][o4][4*j4 + 3]);
            m = dpp_xor1_max(m);
            m = dpp_xor2_max(m);
            if (j4 == 0) gp[t*16 + o4] = m;
            __builtin_amdgcn_sched_barrier(0);
            asm volatile("s_waitcnt lgkmcnt(0)" ::: "memory");
            __builtin_amdgcn_sched_barrier(0);
        }
    }
}

// ---------------------------------------------------------------------------
// k_mid: combine half-maxima -> h1, conv2 (folded) -> h2 written as bf16
// hi/lo pair in MFMA A-layout [b][row n (16, row15=0)][k=o2 (128)].
// ---------------------------------------------------------------------------
__global__ __launch_bounds__(256) void k_mid(
    const float* __restrict__ gpart,  // [256][2][15][64]
    const float4* __restrict__ w2q,   // [16][128]
    const float* __restrict__ bias2,  // [128]
    unsigned short* __restrict__ h2h, // [256][16][128] bf16 hi
    unsigned short* __restrict__ h2l) // [256][16][128] bf16 lo
{
    __shared__ float h1s[960];        // [15][64]
    const int tid = threadIdx.x;
    const int b = blockIdx.x;

    const float* gp = gpart + (size_t)b * 1920;
    for (int i = tid; i < 960; i += 256)
        h1s[i] = fmaxf(gp[i], gp[960 + i]);
    __syncthreads();

    for (int idx = tid; idx < 2048; idx += 256) {
        const int o2 = idx & 127, n = idx >> 7;   // n: 0..15
        float val = 0.f;
        if (n < 15) {
            float acc = 0.f;
            #pragma unroll
            for (int cq = 0; cq < 16; ++cq) {
                const float4 h4 = *(const float4*)(&h1s[n*64 + cq*4]);
                const float4 w4 = w2q[cq*128 + o2];
                acc = fmaf(w4.x, h4.x, fmaf(w4.y, h4.y,
                      fmaf(w4.z, h4.z, fmaf(w4.w, h4.w, acc))));
            }
            val = fmaxf(acc + bias2[o2], 0.f);
        }
        const unsigned short hi = bf16r(val);
        const unsigned short lo = bf16r(val - bf2f(hi));
        h2h[(size_t)b*2048 + n*128 + o2] = hi;
        h2l[(size_t)b*2048 + n*128 + o2] = lo;
    }
}

// ---------------------------------------------------------------------------
// k_s3: conv3 via bf16x3-split MFMA + global max over N=15.
// Block = b (256 thr = 4 waves); wave handles 16 N-tiles of 16 o's.
// A[16 rows=points][128 k] from h2h/h2l (frags loaded ONCE, reused 16x).
// B from Bpack (pre-split, per-lane-contiguous).  C row 15 (pad) excluded.
// err ~ lo*lo ~ 2^-18 relative — well inside tolerance.
// ---------------------------------------------------------------------------
__global__ __launch_bounds__(256) void k_s3(
    const unsigned short* __restrict__ h2h,
    const unsigned short* __restrict__ h2l,
    const unsigned short* __restrict__ Bh,
    const unsigned short* __restrict__ Bl,
    const float* __restrict__ bias3,
    float* __restrict__ gout)         // [256,1024]
{
    const int tid = threadIdx.x;
    const int b = blockIdx.x;
    const int wave = tid >> 6, lane = tid & 63;
    const int arow = lane & 15, agrp = lane >> 4;

    short8v ahi[4], alo[4];
    {
        const unsigned short* Ab = h2h + (size_t)b*2048 + arow*128 + agrp*8;
        const unsigned short* Al = h2l + (size_t)b*2048 + arow*128 + agrp*8;
        #pragma unroll
        for (int kt = 0; kt < 4; ++kt) {
            ahi[kt] = *(const short8v*)(Ab + kt*32);
            alo[kt] = *(const short8v*)(Al + kt*32);
        }
    }

    for (int ntl = 0; ntl < 16; ++ntl) {
        const int nt = wave * 16 + ntl;
        f32x4 a0 = {0.f, 0.f, 0.f, 0.f};
        f32x4 a1 = a0, a2 = a0;
        #pragma unroll
        for (int kt = 0; kt < 4; ++kt) {
            const size_t off = (((size_t)kt*64 + nt)*64 + lane) * 8;
            const short8v bh = *(const short8v*)(Bh + off);
            const short8v bl = *(const short8v*)(Bl + off);
            a0 = __builtin_amdgcn_mfma_f32_16x16x32_bf16(ahi[kt], bh, a0, 0, 0, 0);
            a1 = __builtin_amdgcn_mfma_f32_16x16x32_bf16(ahi[kt], bl, a1, 0, 0, 0);
            a2 = __builtin_amdgcn_mfma_f32_16x16x32_bf16(alo[kt], bh, a2, 0, 0, 0);
        }
        const float r0 = a0[0] + a1[0] + a2[0];
        const float r1 = a0[1] + a1[1] + a2[1];
        const float r2 = a0[2] + a1[2] + a2[2];
        const float r3 = a0[3] + a1[3] + a2[3];
        float m = fmaxf(fmaxf(r0, r1), r2);
        if (agrp != 3) m = fmaxf(m, r3);          // exclude pad row 15
        m = fmaxf(m, __shfl_xor(m, 16));
        m = fmaxf(m, __shfl_xor(m, 32));
        if (lane < 16)
            gout[(size_t)b*1024 + nt*16 + lane] = m + bias3[nt*16 + lane];
    }
}

// ---------------------------------------------------------------------------
// k_fc1p: fc1 split-K=2 raw partials.  grid (8,16,2), 32x32 tile.
// ---------------------------------------------------------------------------
__global__ __launch_bounds__(256) void k_fc1p(
    const float* __restrict__ A,      // g [256][1024]
    const float* __restrict__ W,      // wf1 [512][1024]
    float* __restrict__ P)            // [2][256][512]
{
    __shared__ float As[32][36];
    __shared__ float Ws[32][36];

    const int tid = threadIdx.x;
    const int bm = blockIdx.x * 32, bn = blockIdx.y * 32;
    const int ks = blockIdx.z;
    const int ml = (tid >> 4) * 2, nl = (tid & 15) * 2;
    const int row = tid >> 3, kq = (tid & 7) * 4;

    float acc00 = 0.f, acc01 = 0.f, acc10 = 0.f, acc11 = 0.f;

    for (int k0 = 0; k0 < 512; k0 += 32) {
        const int ch = ks * 512 + k0 + kq;
        const float4 av = *(const float4*)(A + (size_t)(bm + row) * 1024 + ch);
        const float4 wv = *(const float4*)(W + (size_t)(bn + row) * 1024 + ch);
        __syncthreads();
        *(float4*)(&As[row][kq]) = av;
        *(float4*)(&Ws[row][kq]) = wv;
        __syncthreads();
        const float4* a0p = (const float4*)(&As[ml][0]);
        const float4* a1p = (const float4*)(&As[ml + 1][0]);
        const float4* b0p = (const float4*)(&Ws[nl][0]);
        const float4* b1p = (const float4*)(&Ws[nl + 1][0]);
        #pragma unroll
        for (int q = 0; q < 8; ++q) {
            const float4 a0 = a0p[q], a1 = a1p[q], b0 = b0p[q], b1 = b1p[q];
            acc00 = fmaf(a0.x, b0.x, fmaf(a0.y, b0.y, fmaf(a0.z, b0.z, fmaf(a0.w, b0.w, acc00))));
            acc01 = fmaf(a0.x, b1.x, fmaf(a0.y, b1.y, fmaf(a0.z, b1.z, fmaf(a0.w, b1.w, acc01))));
            acc10 = fmaf(a1.x, b0.x, fmaf(a1.y, b0.y, fmaf(a1.z, b0.z, fmaf(a1.w, b0.w, acc10))));
            acc11 = fmaf(a1.x, b1.x, fmaf(a1.y, b1.y, fmaf(a1.z, b1.z, fmaf(a1.w, b1.w, acc11))));
        }
    }
    float* p0 = P + (size_t)ks * 131072 + (size_t)(bm + ml) * 512 + bn + nl;
    p0[0] = acc00; p0[1] = acc01;
    float* p1 = p0 + 512;
    p1[0] = acc10; p1[1] = acc11;
}

// ---------------------------------------------------------------------------
// k_fc2p: fc2 split-K=2; A-tile finishes f1 (BN+ReLU+combine) on the fly.
// ---------------------------------------------------------------------------
__global__ __launch_bounds__(256) void k_fc2p(
    const float* __restrict__ fp,     // [2][256][512]
    const float* __restrict__ sf1, const float* __restrict__ cf1,
    const float* __restrict__ W,      // wf2 [256][512]
    float* __restrict__ P2)           // [2][256][256]
{
    __shared__ float As[32][36];
    __shared__ float Ws[32][36];

    const int tid = threadIdx.x;
    const int bm = blockIdx.x * 32, bn = blockIdx.y * 32;
    const int ks = blockIdx.z;
    const int ml = (tid >> 4) * 2, nl = (tid & 15) * 2;
    const int row = tid >> 3, kq = (tid & 7) * 4;

    float acc00 = 0.f, acc01 = 0.f, acc10 = 0.f, acc11 = 0.f;

    for (int k0 = 0; k0 < 256; k0 += 32) {
        const int ch = ks * 256 + k0 + kq;
        const float4 p0 = *(const float4*)(fp + (size_t)(bm + row) * 512 + ch);
        const float4 p1 = *(const float4*)(fp + 131072 + (size_t)(bm + row) * 512 + ch);
        const float4 s4 = *(const float4*)(sf1 + ch);
        const float4 c4 = *(const float4*)(cf1 + ch);
        float4 av;
        av.x = fmaxf(fmaf(s4.x, p0.x + p1.x, c4.x), 0.f);
        av.y = fmaxf(fmaf(s4.y, p0.y + p1.y, c4.y), 0.f);
        av.z = fmaxf(fmaf(s4.z, p0.z + p1.z, c4.z), 0.f);
        av.w = fmaxf(fmaf(s4.w, p0.w + p1.w, c4.w), 0.f);
        const float4 wv = *(const float4*)(W + (size_t)(bn + row) * 512 + ch);
        __syncthreads();
        *(float4*)(&As[row][kq]) = av;
        *(float4*)(&Ws[row][kq]) = wv;
        __syncthreads();
        const float4* a0p = (const float4*)(&As[ml][0]);
        const float4* a1p = (const float4*)(&As[ml + 1][0]);
        const float4* b0p = (const float4*)(&Ws[nl][0]);
        const float4* b1p = (const float4*)(&Ws[nl + 1][0]);
        #pragma unroll
        for (int q = 0; q < 8; ++q) {
            const float4 a0 = a0p[q], a1 = a1p[q], b0 = b0p[q], b1 = b1p[q];
            acc00 = fmaf(a0.x, b0.x, fmaf(a0.y, b0.y, fmaf(a0.z, b0.z, fmaf(a0.w, b0.w, acc00))));
            acc01 = fmaf(a0.x, b1.x, fmaf(a0.y, b1.y, fmaf(a0.z, b1.z, fmaf(a0.w, b1.w, acc01))));
            acc10 = fmaf(a1.x, b0.x, fmaf(a1.y, b0.y, fmaf(a1.z, b0.z, fmaf(a1.w, b0.w, acc10))));
            acc11 = fmaf(a1.x, b1.x, fmaf(a1.y, b1.y, fmaf(a1.z, b1.z, fmaf(a1.w, b1.w, acc11))));
        }
    }
    float* q0 = P2 + (size_t)ks * 65536 + (size_t)(bm + ml) * 256 + bn + nl;
    q0[0] = acc00; q0[1] = acc01;
    float* q1 = q0 + 256;
    q1[0] = acc10; q1[1] = acc11;
}

// ---------------------------------------------------------------------------
// k_ep2: f2 = relu(sf2*(P2[0]+P2[1]) + cf2)
// ---------------------------------------------------------------------------
__global__ __launch_bounds__(256) void k_ep2(
    const float* __restrict__ P2, const float* __restrict__ sf2,
    const float* __restrict__ cf2, float* __restrict__ f2)
{
    const int i = blockIdx.x * 256 + threadIdx.x;
    const int n = i & 255;
    const float v = P2[i] + P2[65536 + i];
    f2[i] = fmaxf(fmaf(sf2[n], v, cf2[n]), 0.f);
}

// ---------------------------------------------------------------------------
// k_fc3: C = A*W^T + bias
// ---------------------------------------------------------------------------
__global__ __launch_bounds__(256) void k_fc3(
    const float* __restrict__ A, const float* __restrict__ W,
    const float* __restrict__ bias, float* __restrict__ C, int K, int Nc)
{
    __shared__ float As[32][36];
    __shared__ float Ws[32][36];

    const int tid = threadIdx.x;
    const int bm = blockIdx.x * 32, bn = blockIdx.y * 32;
    const int ml = (tid >> 4) * 2, nl = (tid & 15) * 2;
    const int row = tid >> 3, kq = (tid & 7) * 4;

    float acc00 = 0.f, acc01 = 0.f, acc10 = 0.f, acc11 = 0.f;

    for (int k0 = 0; k0 < K; k0 += 32) {
        const float4 av = *(const float4*)(A + (size_t)(bm + row) * K + k0 + kq);
        const float4 wv = *(const float4*)(W + (size_t)(bn + row) * K + k0 + kq);
        __syncthreads();
        *(float4*)(&As[row][kq]) = av;
        *(float4*)(&Ws[row][kq]) = wv;
        __syncthreads();
        const float4* a0p = (const float4*)(&As[ml][0]);
        const float4* a1p = (const float4*)(&As[ml + 1][0]);
        const float4* b0p = (const float4*)(&Ws[nl][0]);
        const float4* b1p = (const float4*)(&Ws[nl + 1][0]);
        #pragma unroll
        for (int q = 0; q < 8; ++q) {
            const float4 a0 = a0p[q], a1 = a1p[q], b0 = b0p[q], b1 = b1p[q];
            acc00 = fmaf(a0.x, b0.x, fmaf(a0.y, b0.y, fmaf(a0.z, b0.z, fmaf(a0.w, b0.w, acc00))));
            acc01 = fmaf(a0.x, b1.x, fmaf(a0.y, b1.y, fmaf(a0.z, b1.z, fmaf(a0.w, b1.w, acc01))));
            acc10 = fmaf(a1.x, b0.x, fmaf(a1.y, b0.y, fmaf(a1.z, b0.z, fmaf(a1.w, b0.w, acc10))));
            acc11 = fmaf(a1.x, b1.x, fmaf(a1.y, b1.y, fmaf(a1.z, b1.z, fmaf(a1.w, b1.w, acc11))));
        }
    }

    const int n0 = bn + nl, n1 = n0 + 1;
    float* cr0 = C + (size_t)(bm + ml) * Nc + n0;
    cr0[0] = acc00 + bias[n0]; cr0[1] = acc01 + bias[n1];
    float* cr1 = C + (size_t)(bm + ml + 1) * Nc + n0;
    cr1[0] = acc10 + bias[n0]; cr1[1] = acc11 + bias[n1];
}

// ---------------------------------------------------------------------------
extern "C" void kernel_launch(void* const* d_in, const int* in_sizes, int n_in,
                              void* d_out, int out_size, void* d_ws, size_t ws_size,
                              hipStream_t stream)
{
    const float* pts     = (const float*)d_in[0];
    const float* info    = (const float*)d_in[2];
    const float* w_info  = (const float*)d_in[3];
    const float* b_info  = (const float*)d_in[4];
    const float* g_info  = (const float*)d_in[5];
    const float* be_info = (const float*)d_in[6];
    const float* m_info  = (const float*)d_in[7];
    const float* v_info  = (const float*)d_in[8];
    const float* w2      = (const float*)d_in[9];
    const float* b2      = (const float*)d_in[10];
    const float* g2      = (const float*)d_in[11];
    const float* be2     = (const float*)d_in[12];
    const float* m2      = (const float*)d_in[13];
    const float* v2      = (const float*)d_in[14];
    const float* w3      = (const float*)d_in[15];
    const float* b3      = (const float*)d_in[16];
    const float* g3      = (const float*)d_in[17];
    const float* be3     = (const float*)d_in[18];
    const float* m3      = (const float*)d_in[19];
    const float* v3      = (const float*)d_in[20];
    const float* wf1     = (const float*)d_in[21];
    const float* bf1     = (const float*)d_in[22];
    const float* gf1     = (const float*)d_in[23];
    const float* bef1    = (const float*)d_in[24];
    const float* mf1     = (const float*)d_in[25];
    const float* vf1     = (const float*)d_in[26];
    const float* wf2     = (const float*)d_in[27];
    const float* bf2     = (const float*)d_in[28];
    const float* gf2     = (const float*)d_in[29];
    const float* bef2    = (const float*)d_in[30];
    const float* mf2     = (const float*)d_in[31];
    const float* vf2     = (const float*)d_in[32];
    const float* wf3     = (const float*)d_in[33];
    const float* bf3     = (const float*)d_in[34];

    float* ws = (float*)d_ws;
    // float-offset layout (launches serialize: reuse only across kernels):
    float*          gpart = ws;                                  // [0..491520)  edge->mid
    unsigned short* h2h   = (unsigned short*)(ws + 491520);      // 524288 bf16 (262144 fslots)
    unsigned short* h2l   = (unsigned short*)(ws + 753664);      // 524288 bf16
    float*          g     = ws + 1015808;                        // 262144
    unsigned short* Bh    = (unsigned short*)(ws + 1277952);     // 131072 bf16 (65536 fslots)
    unsigned short* Bl    = (unsigned short*)(ws + 1343488);     // 131072 bf16
    float*          bias3 = ws + 1409024;                        // 1024
    float4*         w2q   = (float4*)(ws + 1410048);             // 8192
    float*          bias2 = ws + 1418240;                        // 128
    float4*         cTab4 = (float4*)(ws + 1418368);             // 256
    float4*         qTab4 = (float4*)(ws + 1418624);             // 256
    float*          sf1   = ws + 1418880;                        // 512
    float*          cf1   = ws + 1419392;                        // 512
    float*          sf2   = ws + 1419904;                        // 256
    float*          cf2   = ws + 1420160;                        // 256
    float*          fp    = ws;                                  // reuse gpart (dead after k_mid)
    float*          P2    = ws + 262144;                         // reuse gpart tail

    float* ret = (float*)d_out;            // [256, 800]
    float* f2  = ret + 256 * 800;          // [256, 256]

    k_pre<<<66, 256, 0, stream>>>(
        w3, b3, g3, be3, m3, v3,
        w2, b2, g2, be2, m2, v2,
        w_info, b_info, g_info, be_info, m_info, v_info,
        bf1, gf1, bef1, mf1, vf1,
        bf2, gf2, bef2, mf2, vf2,
        Bh, Bl, bias3, w2q, bias2, cTab4, qTab4, sf1, cf1, sf2, cf2);

    k_edge<<<512, 1024, 0, stream>>>(pts, info, cTab4, qTab4, gpart);

    k_mid<<<256, 256, 0, stream>>>(gpart, w2q, bias2, h2h, h2l);

    k_s3<<<256, 256, 0, stream>>>(h2h, h2l, Bh, Bl, bias3, g);

    k_fc1p<<<dim3(8, 16, 2), 256, 0, stream>>>(g, wf1, fp);

    k_fc2p<<<dim3(8, 8, 2), 256, 0, stream>>>(fp, sf1, cf1, wf2, P2);

    k_ep2<<<256, 256, 0, stream>>>(P2, sf2, cf2, f2);

    k_fc3<<<dim3(8, 25), 256, 0, stream>>>(f2, wf3, bf3, ret, 256, 800);
}

// Round 10
// 112.261 us; speedup vs baseline: 2.0040x; 1.0935x over previous
//
#include <hip/hip_runtime.h>
#include <math.h>

#define EPS 1e-5f

typedef __attribute__((ext_vector_type(8))) short short8v;
typedef __attribute__((ext_vector_type(4))) float f32x4;

// ---- bf16 split helpers (RNE) ----
__device__ __forceinline__ unsigned short bf16r(float x) {
    unsigned u = __float_as_uint(x);
    return (unsigned short)((u + 0x7FFFu + ((u >> 16) & 1u)) >> 16);
}
__device__ __forceinline__ float bf2f(unsigned short h) {
    return __uint_as_float(((unsigned)h) << 16);
}

// ---- DPP quad-reduction helpers ----
__device__ __forceinline__ float dpp_xor1_max(float x) {
    int xi = __float_as_int(x);
    int yi = __builtin_amdgcn_update_dpp(xi, xi, 0xB1, 0xF, 0xF, true);
    return fmaxf(x, __int_as_float(yi));
}
__device__ __forceinline__ float dpp_xor2_max(float x) {
    int xi = __float_as_int(x);
    int yi = __builtin_amdgcn_update_dpp(xi, xi, 0x4E, 0xF, 0xF, true);
    return fmaxf(x, __int_as_float(yi));
}

// ---------------------------------------------------------------------------
// k_pre (66 blocks): Bpack (conv3 bf16-split B), w2q/bias2 (conv2 fold),
// cTab4/qTab4 (edge fold), bias3, sf1/cf1, sf2/cf2.
// ---------------------------------------------------------------------------
__global__ __launch_bounds__(256) void k_pre(
    const float* __restrict__ w3, const float* __restrict__ b3,
    const float* __restrict__ g3, const float* __restrict__ be3,
    const float* __restrict__ m3, const float* __restrict__ v3,
    const float* __restrict__ w2, const float* __restrict__ b2,
    const float* __restrict__ g2, const float* __restrict__ be2,
    const float* __restrict__ m2, const float* __restrict__ v2,
    const float* __restrict__ w_info, const float* __restrict__ b_info,
    const float* __restrict__ g_info, const float* __restrict__ be_info,
    const float* __restrict__ m_info, const float* __restrict__ v_info,
    const float* __restrict__ bf1, const float* __restrict__ gf1,
    const float* __restrict__ bef1, const float* __restrict__ mf1,
    const float* __restrict__ vf1,
    const float* __restrict__ bf2, const float* __restrict__ gf2,
    const float* __restrict__ bef2, const float* __restrict__ mf2,
    const float* __restrict__ vf2,
    unsigned short* __restrict__ Bh, unsigned short* __restrict__ Bl,
    float* __restrict__ bias3,
    float4* __restrict__ w2q, float* __restrict__ bias2,
    float4* __restrict__ cTab4, float4* __restrict__ qTab4,
    float* __restrict__ sf1, float* __restrict__ cf1,
    float* __restrict__ sf2, float* __restrict__ cf2)
{
    const int blk = blockIdx.x, tid = threadIdx.x;
    if (blk < 64) {
        const int t = blk * 256 + tid;        // (kt,nt,lane)
        const int kt = t >> 12;
        const int nt = (t >> 6) & 63;
        const int lane = t & 63;
        const int o  = nt * 16 + (lane & 15);
        const int kb = kt * 32 + ((lane >> 4) << 3);
        const float a3 = g3[o] * rsqrtf(v3[o] + EPS);
        unsigned short hi[8], lo[8];
        #pragma unroll
        for (int j = 0; j < 8; ++j) {
            const float wv = a3 * w3[(size_t)o * 128 + kb + j];
            hi[j] = bf16r(wv);
            lo[j] = bf16r(wv - bf2f(hi[j]));
        }
        #pragma unroll
        for (int j = 0; j < 8; ++j) {
            Bh[(size_t)t * 8 + j] = hi[j];
            Bl[(size_t)t * 8 + j] = lo[j];
        }
    } else if (blk == 64) {
        for (int idx = tid; idx < 2048; idx += 256) {
            const int o2 = idx & 127, cq = idx >> 7;
            const float a2 = g2[o2] * rsqrtf(v2[o2] + EPS);
            const float4 w = *(const float4*)(w2 + (size_t)o2 * 64 + cq * 4);
            w2q[cq * 128 + o2] = make_float4(a2 * w.x, a2 * w.y, a2 * w.z, a2 * w.w);
        }
        if (tid < 128) {
            const float a2 = g2[tid] * rsqrtf(v2[tid] + EPS);
            bias2[tid] = a2 * (b2[tid] - m2[tid]) + be2[tid];
        }
    } else {
        if (tid < 64) {
            const int o = tid;
            const float w0 = w_info[o*6+0], w1 = w_info[o*6+1], w2c = w_info[o*6+2];
            const float w3c = w_info[o*6+3], w4 = w_info[o*6+4], w5 = w_info[o*6+5];
            const float a = g_info[o] * rsqrtf(v_info[o] + EPS);
            cTab4[o] = make_float4(a*w0, a*w1, a*w2c, 0.f);
            qTab4[o] = make_float4(a*(w3c-w0), a*(w4-w1), a*(w5-w2c),
                                   a*(b_info[o]-m_info[o]) + be_info[o]);
        }
        for (int c = tid; c < 1024; c += 256) {
            const float a3 = g3[c] * rsqrtf(v3[c] + EPS);
            bias3[c] = a3 * (b3[c] - m3[c]) + be3[c];
        }
        for (int c = tid; c < 512; c += 256) {
            const float s = gf1[c] * rsqrtf(vf1[c] + EPS);
            sf1[c] = s;
            cf1[c] = s * (bf1[c] - mf1[c]) + bef1[c];
        }
        {
            const int c = tid;
            const float s = gf2[c] * rsqrtf(vf2[c] + EPS);
            sf2[c] = s;
            cf2[c] = s * (bf2[c] - mf2[c]) + bef2[c];
        }
    }
}

// ---------------------------------------------------------------------------
// k_edge1b: FUSED edge-conv (6->64) + BN + ReLU + full max over K=520 +
// conv2 (64->128) + BN + ReLU + bf16 hi/lo split for MFMA.
// ONE BLOCK PER b (256 blocks = 1/CU, single round), 1024 thr.
// Full info[b] (93.6KB) staged in LDS; wave = n, lane = k.
// R9 lesson: NO second launch-bounds arg (it scratch-spilled the 80-reg
// state: VGPR=36, 53MB scratch writes); t-loop fully unrolled so every
// array index is compile-time (SROA -> registers).
// ---------------------------------------------------------------------------
__global__ __launch_bounds__(1024) void k_edge1b(
    const float* __restrict__ pts,        // [256,15,3]
    const float* __restrict__ info,       // [256,520,15,3]
    const float4* __restrict__ cTab4,     // [64]
    const float4* __restrict__ qTab4,     // [64]
    const float4* __restrict__ w2q,       // [16][128]
    const float* __restrict__ bias2,      // [128]
    unsigned short* __restrict__ h2h,     // [256][16][128] bf16 hi
    unsigned short* __restrict__ h2l)     // [256][16][128] bf16 lo
{
    __shared__ float ds[23400];           // 93600 B
    __shared__ float part[15][16][17];    // 16320 B
    __shared__ float h1s[960];            // 3840 B   (total 113760 B)

    const int tid = threadIdx.x;
    const int b = blockIdx.x;

    { // coalesced staging of the full 520 k-rows for this b
        const float4* src = (const float4*)(info + (size_t)b * 23400);
        float4* dst = (float4*)ds;
        for (int i = tid; i < 5850; i += 1024) dst[i] = src[i];
    }
    __syncthreads();

    const int wave = tid >> 6, lane = tid & 63;
    if (wave < 15) {
        const int n = wave;
        const float x0 = pts[b*45 + n*3 + 0];
        const float x1 = pts[b*45 + n*3 + 1];
        const float x2 = pts[b*45 + n*3 + 2];

        #pragma unroll
        for (int t = 0; t < 4; ++t) {     // o-tiles of 16 (fully unrolled)
            float c0[16], c1[16], c2[16], bias[16];
            #pragma unroll
            for (int j = 0; j < 16; ++j) {
                const int o = t*16 + j;
                const float4 qv = qTab4[o];
                bias[j] = fmaf(qv.x, x0, fmaf(qv.y, x1, fmaf(qv.z, x2, qv.w)));
                const float4 cv = cTab4[o];
                c0[j] = cv.x; c1[j] = cv.y; c2[j] = cv.z;
            }
            float acc[16];
            #pragma unroll
            for (int j = 0; j < 16; ++j) acc[j] = 0.f;   // relu floor

            for (int kk = lane; kk < 520; kk += 64) {
                const float* p = ds + kk*45 + n*3;       // per-lane LDS read
                const float d0 = p[0], d1 = p[1], d2 = p[2];
                #pragma unroll
                for (int j = 0; j < 16; ++j)
                    acc[j] = fmaxf(acc[j],
                        fmaf(c0[j], d0, fmaf(c1[j], d1, fmaf(c2[j], d2, bias[j]))));
            }
            #pragma unroll
            for (int j = 0; j < 16; ++j) {
                acc[j] = dpp_xor1_max(acc[j]);
                acc[j] = dpp_xor2_max(acc[j]);
            }
            const int q4 = lane >> 2, r4 = lane & 3;
            #pragma unroll
            for (int i = 0; i < 4; ++i) {
                float v = acc[4*i];
                v = (r4 == 1) ? acc[4*i+1] : v;
                v = (r4 == 2) ? acc[4*i+2] : v;
                v = (r4 == 3) ? acc[4*i+3] : v;
                part[n][4*i + r4][q4] = v;
            }
            __builtin_amdgcn_sched_barrier(0);
            asm volatile("s_waitcnt lgkmcnt(0)" ::: "memory");
            __builtin_amdgcn_sched_barrier(0);
            const int o4 = lane >> 2, j4 = lane & 3;
            float m =          part[n][o4][4*j4 + 0];
            m = fmaxf(m, part[n][o4][4*j4 + 1]);
            m = fmaxf(m, part[n][o4][4*j4 + 2]);
            m = fmaxf(m, part[n][o4][4*j4 + 3]);
            m = dpp_xor1_max(m);
            m = dpp_xor2_max(m);
            if (j4 == 0) h1s[n*64 + t*16 + o4] = m;
            __builtin_amdgcn_sched_barrier(0);
            asm volatile("s_waitcnt lgkmcnt(0)" ::: "memory");
            __builtin_amdgcn_sched_barrier(0);
        }
    }
    __syncthreads();

    // conv2: 16x128 outputs (row 15 = pad 0), bf16 hi/lo split write
    for (int idx = tid; idx < 2048; idx += 1024) {
        const int o2 = idx & 127, n = idx >> 7;   // n: 0..15
        float val = 0.f;
        if (n < 15) {
            float acc = 0.f;
            #pragma unroll
            for (int cq = 0; cq < 16; ++cq) {
                const float4 h4 = *(const float4*)(&h1s[n*64 + cq*4]);
                const float4 w4 = w2q[cq*128 + o2];
                acc = fmaf(w4.x, h4.x, fmaf(w4.y, h4.y,
                      fmaf(w4.z, h4.z, fmaf(w4.w, h4.w, acc))));
            }
            val = fmaxf(acc + bias2[o2], 0.f);
        }
        const unsigned short hi = bf16r(val);
        const unsigned short lo = bf16r(val - bf2f(hi));
        h2h[(size_t)b*2048 + n*128 + o2] = hi;
        h2l[(size_t)b*2048 + n*128 + o2] = lo;
    }
}

// ---------------------------------------------------------------------------
// k_s3: conv3 via bf16x3-split MFMA + global max over N=15.  (validated R9)
// ---------------------------------------------------------------------------
__global__ __launch_bounds__(256) void k_s3(
    const unsigned short* __restrict__ h2h,
    const unsigned short* __restrict__ h2l,
    const unsigned short* __restrict__ Bh,
    const unsigned short* __restrict__ Bl,
    const float* __restrict__ bias3,
    float* __restrict__ gout)         // [256,1024]
{
    const int tid = threadIdx.x;
    const int b = blockIdx.x;
    const int wave = tid >> 6, lane = tid & 63;
    const int arow = lane & 15, agrp = lane >> 4;

    short8v ahi[4], alo[4];
    {
        const unsigned short* Ab = h2h + (size_t)b*2048 + arow*128 + agrp*8;
        const unsigned short* Al = h2l + (size_t)b*2048 + arow*128 + agrp*8;
        #pragma unroll
        for (int kt = 0; kt < 4; ++kt) {
            ahi[kt] = *(const short8v*)(Ab + kt*32);
            alo[kt] = *(const short8v*)(Al + kt*32);
        }
    }

    for (int ntl = 0; ntl < 16; ++ntl) {
        const int nt = wave * 16 + ntl;
        f32x4 a0 = {0.f, 0.f, 0.f, 0.f};
        f32x4 a1 = a0, a2 = a0;
        #pragma unroll
        for (int kt = 0; kt < 4; ++kt) {
            const size_t off = (((size_t)kt*64 + nt)*64 + lane) * 8;
            const short8v bh = *(const short8v*)(Bh + off);
            const short8v bl = *(const short8v*)(Bl + off);
            a0 = __builtin_amdgcn_mfma_f32_16x16x32_bf16(ahi[kt], bh, a0, 0, 0, 0);
            a1 = __builtin_amdgcn_mfma_f32_16x16x32_bf16(ahi[kt], bl, a1, 0, 0, 0);
            a2 = __builtin_amdgcn_mfma_f32_16x16x32_bf16(alo[kt], bh, a2, 0, 0, 0);
        }
        const float r0 = a0[0] + a1[0] + a2[0];
        const float r1 = a0[1] + a1[1] + a2[1];
        const float r2 = a0[2] + a1[2] + a2[2];
        const float r3 = a0[3] + a1[3] + a2[3];
        float m = fmaxf(fmaxf(r0, r1), r2);
        if (agrp != 3) m = fmaxf(m, r3);          // exclude pad row 15
        m = fmaxf(m, __shfl_xor(m, 16));
        m = fmaxf(m, __shfl_xor(m, 32));
        if (lane < 16)
            gout[(size_t)b*1024 + nt*16 + lane] = m + bias3[nt*16 + lane];
    }
}

// ---------------------------------------------------------------------------
// k_fc1p: fc1 split-K=2 raw partials.  grid (8,16,2), 32x32 tile.
// ---------------------------------------------------------------------------
__global__ __launch_bounds__(256) void k_fc1p(
    const float* __restrict__ A,      // g [256][1024]
    const float* __restrict__ W,      // wf1 [512][1024]
    float* __restrict__ P)            // [2][256][512]
{
    __shared__ float As[32][36];
    __shared__ float Ws[32][36];

    const int tid = threadIdx.x;
    const int bm = blockIdx.x * 32, bn = blockIdx.y * 32;
    const int ks = blockIdx.z;
    const int ml = (tid >> 4) * 2, nl = (tid & 15) * 2;
    const int row = tid >> 3, kq = (tid & 7) * 4;

    float acc00 = 0.f, acc01 = 0.f, acc10 = 0.f, acc11 = 0.f;

    for (int k0 = 0; k0 < 512; k0 += 32) {
        const int ch = ks * 512 + k0 + kq;
        const float4 av = *(const float4*)(A + (size_t)(bm + row) * 1024 + ch);
        const float4 wv = *(const float4*)(W + (size_t)(bn + row) * 1024 + ch);
        __syncthreads();
        *(float4*)(&As[row][kq]) = av;
        *(float4*)(&Ws[row][kq]) = wv;
        __syncthreads();
        const float4* a0p = (const float4*)(&As[ml][0]);
        const float4* a1p = (const float4*)(&As[ml + 1][0]);
        const float4* b0p = (const float4*)(&Ws[nl][0]);
        const float4* b1p = (const float4*)(&Ws[nl + 1][0]);
        #pragma unroll
        for (int q = 0; q < 8; ++q) {
            const float4 a0 = a0p[q], a1 = a1p[q], b0 = b0p[q], b1 = b1p[q];
            acc00 = fmaf(a0.x, b0.x, fmaf(a0.y, b0.y, fmaf(a0.z, b0.z, fmaf(a0.w, b0.w, acc00))));
            acc01 = fmaf(a0.x, b1.x, fmaf(a0.y, b1.y, fmaf(a0.z, b1.z, fmaf(a0.w, b1.w, acc01))));
            acc10 = fmaf(a1.x, b0.x, fmaf(a1.y, b0.y, fmaf(a1.z, b0.z, fmaf(a1.w, b0.w, acc10))));
            acc11 = fmaf(a1.x, b1.x, fmaf(a1.y, b1.y, fmaf(a1.z, b1.z, fmaf(a1.w, b1.w, acc11))));
        }
    }
    float* p0 = P + (size_t)ks * 131072 + (size_t)(bm + ml) * 512 + bn + nl;
    p0[0] = acc00; p0[1] = acc01;
    float* p1 = p0 + 512;
    p1[0] = acc10; p1[1] = acc11;
}

// ---------------------------------------------------------------------------
// k_fc2p: fc2 split-K=2; A-tile finishes f1 (BN+ReLU+combine) on the fly.
// ---------------------------------------------------------------------------
__global__ __launch_bounds__(256) void k_fc2p(
    const float* __restrict__ fp,     // [2][256][512]
    const float* __restrict__ sf1, const float* __restrict__ cf1,
    const float* __restrict__ W,      // wf2 [256][512]
    float* __restrict__ P2)           // [2][256][256]
{
    __shared__ float As[32][36];
    __shared__ float Ws[32][36];

    const int tid = threadIdx.x;
    const int bm = blockIdx.x * 32, bn = blockIdx.y * 32;
    const int ks = blockIdx.z;
    const int ml = (tid >> 4) * 2, nl = (tid & 15) * 2;
    const int row = tid >> 3, kq = (tid & 7) * 4;

    float acc00 = 0.f, acc01 = 0.f, acc10 = 0.f, acc11 = 0.f;

    for (int k0 = 0; k0 < 256; k0 += 32) {
        const int ch = ks * 256 + k0 + kq;
        const float4 p0 = *(const float4*)(fp + (size_t)(bm + row) * 512 + ch);
        const float4 p1 = *(const float4*)(fp + 131072 + (size_t)(bm + row) * 512 + ch);
        const float4 s4 = *(const float4*)(sf1 + ch);
        const float4 c4 = *(const float4*)(cf1 + ch);
        float4 av;
        av.x = fmaxf(fmaf(s4.x, p0.x + p1.x, c4.x), 0.f);
        av.y = fmaxf(fmaf(s4.y, p0.y + p1.y, c4.y), 0.f);
        av.z = fmaxf(fmaf(s4.z, p0.z + p1.z, c4.z), 0.f);
        av.w = fmaxf(fmaf(s4.w, p0.w + p1.w, c4.w), 0.f);
        const float4 wv = *(const float4*)(W + (size_t)(bn + row) * 512 + ch);
        __syncthreads();
        *(float4*)(&As[row][kq]) = av;
        *(float4*)(&Ws[row][kq]) = wv;
        __syncthreads();
        const float4* a0p = (const float4*)(&As[ml][0]);
        const float4* a1p = (const float4*)(&As[ml + 1][0]);
        const float4* b0p = (const float4*)(&Ws[nl][0]);
        const float4* b1p = (const float4*)(&Ws[nl + 1][0]);
        #pragma unroll
        for (int q = 0; q < 8; ++q) {
            const float4 a0 = a0p[q], a1 = a1p[q], b0 = b0p[q], b1 = b1p[q];
            acc00 = fmaf(a0.x, b0.x, fmaf(a0.y, b0.y, fmaf(a0.z, b0.z, fmaf(a0.w, b0.w, acc00))));
            acc01 = fmaf(a0.x, b1.x, fmaf(a0.y, b1.y, fmaf(a0.z, b1.z, fmaf(a0.w, b1.w, acc01))));
            acc10 = fmaf(a1.x, b0.x, fmaf(a1.y, b0.y, fmaf(a1.z, b0.z, fmaf(a1.w, b0.w, acc10))));
            acc11 = fmaf(a1.x, b1.x, fmaf(a1.y, b1.y, fmaf(a1.z, b1.z, fmaf(a1.w, b1.w, acc11))));
        }
    }
    float* q0 = P2 + (size_t)ks * 65536 + (size_t)(bm + ml) * 256 + bn + nl;
    q0[0] = acc00; q0[1] = acc01;
    float* q1 = q0 + 256;
    q1[0] = acc10; q1[1] = acc11;
}

// ---------------------------------------------------------------------------
// k_ep2: f2 = relu(sf2*(P2[0]+P2[1]) + cf2)
// ---------------------------------------------------------------------------
__global__ __launch_bounds__(256) void k_ep2(
    const float* __restrict__ P2, const float* __restrict__ sf2,
    const float* __restrict__ cf2, float* __restrict__ f2)
{
    const int i = blockIdx.x * 256 + threadIdx.x;
    const int n = i & 255;
    const float v = P2[i] + P2[65536 + i];
    f2[i] = fmaxf(fmaf(sf2[n], v, cf2[n]), 0.f);
}

// ---------------------------------------------------------------------------
// k_fc3: C = A*W^T + bias
// ---------------------------------------------------------------------------
__global__ __launch_bounds__(256) void k_fc3(
    const float* __restrict__ A, const float* __restrict__ W,
    const float* __restrict__ bias, float* __restrict__ C, int K, int Nc)
{
    __shared__ float As[32][36];
    __shared__ float Ws[32][36];

    const int tid = threadIdx.x;
    const int bm = blockIdx.x * 32, bn = blockIdx.y * 32;
    const int ml = (tid >> 4) * 2, nl = (tid & 15) * 2;
    const int row = tid >> 3, kq = (tid & 7) * 4;

    float acc00 = 0.f, acc01 = 0.f, acc10 = 0.f, acc11 = 0.f;

    for (int k0 = 0; k0 < K; k0 += 32) {
        const float4 av = *(const float4*)(A + (size_t)(bm + row) * K + k0 + kq);
        const float4 wv = *(const float4*)(W + (size_t)(bn + row) * K + k0 + kq);
        __syncthreads();
        *(float4*)(&As[row][kq]) = av;
        *(float4*)(&Ws[row][kq]) = wv;
        __syncthreads();
        const float4* a0p = (const float4*)(&As[ml][0]);
        const float4* a1p = (const float4*)(&As[ml + 1][0]);
        const float4* b0p = (const float4*)(&Ws[nl][0]);
        const float4* b1p = (const float4*)(&Ws[nl + 1][0]);
        #pragma unroll
        for (int q = 0; q < 8; ++q) {
            const float4 a0 = a0p[q], a1 = a1p[q], b0 = b0p[q], b1 = b1p[q];
            acc00 = fmaf(a0.x, b0.x, fmaf(a0.y, b0.y, fmaf(a0.z, b0.z, fmaf(a0.w, b0.w, acc00))));
            acc01 = fmaf(a0.x, b1.x, fmaf(a0.y, b1.y, fmaf(a0.z, b1.z, fmaf(a0.w, b1.w, acc01))));
            acc10 = fmaf(a1.x, b0.x, fmaf(a1.y, b0.y, fmaf(a1.z, b0.z, fmaf(a1.w, b0.w, acc10))));
            acc11 = fmaf(a1.x, b1.x, fmaf(a1.y, b1.y, fmaf(a1.z, b1.z, fmaf(a1.w, b1.w, acc11))));
        }
    }

    const int n0 = bn + nl, n1 = n0 + 1;
    float* cr0 = C + (size_t)(bm + ml) * Nc + n0;
    cr0[0] = acc00 + bias[n0]; cr0[1] = acc01 + bias[n1];
    float* cr1 = C + (size_t)(bm + ml + 1) * Nc + n0;
    cr1[0] = acc10 + bias[n0]; cr1[1] = acc11 + bias[n1];
}

// ---------------------------------------------------------------------------
extern "C" void kernel_launch(void* const* d_in, const int* in_sizes, int n_in,
                              void* d_out, int out_size, void* d_ws, size_t ws_size,
                              hipStream_t stream)
{
    const float* pts     = (const float*)d_in[0];
    const float* info    = (const float*)d_in[2];
    const float* w_info  = (const float*)d_in[3];
    const float* b_info  = (const float*)d_in[4];
    const float* g_info  = (const float*)d_in[5];
    const float* be_info = (const float*)d_in[6];
    const float* m_info  = (const float*)d_in[7];
    const float* v_info  = (const float*)d_in[8];
    const float* w2      = (const float*)d_in[9];
    const float* b2      = (const float*)d_in[10];
    const float* g2      = (const float*)d_in[11];
    const float* be2     = (const float*)d_in[12];
    const float* m2      = (const float*)d_in[13];
    const float* v2      = (const float*)d_in[14];
    const float* w3      = (const float*)d_in[15];
    const float* b3      = (const float*)d_in[16];
    const float* g3      = (const float*)d_in[17];
    const float* be3     = (const float*)d_in[18];
    const float* m3      = (const float*)d_in[19];
    const float* v3      = (const float*)d_in[20];
    const float* wf1     = (const float*)d_in[21];
    const float* bf1     = (const float*)d_in[22];
    const float* gf1     = (const float*)d_in[23];
    const float* bef1    = (const float*)d_in[24];
    const float* mf1     = (const float*)d_in[25];
    const float* vf1     = (const float*)d_in[26];
    const float* wf2     = (const float*)d_in[27];
    const float* bf2     = (const float*)d_in[28];
    const float* gf2     = (const float*)d_in[29];
    const float* bef2    = (const float*)d_in[30];
    const float* mf2     = (const float*)d_in[31];
    const float* vf2     = (const float*)d_in[32];
    const float* wf3     = (const float*)d_in[33];
    const float* bf3     = (const float*)d_in[34];

    float* ws = (float*)d_ws;
    unsigned short* h2h   = (unsigned short*)(ws + 491520);      // 524288 bf16
    unsigned short* h2l   = (unsigned short*)(ws + 753664);      // 524288 bf16
    float*          g     = ws + 1015808;                        // 262144
    unsigned short* Bh    = (unsigned short*)(ws + 1277952);     // 131072 bf16
    unsigned short* Bl    = (unsigned short*)(ws + 1343488);     // 131072 bf16
    float*          bias3 = ws + 1409024;                        // 1024
    float4*         w2q   = (float4*)(ws + 1410048);             // 8192
    float*          bias2 = ws + 1418240;                        // 128
    float4*         cTab4 = (float4*)(ws + 1418368);             // 256
    float4*         qTab4 = (float4*)(ws + 1418624);             // 256
    float*          sf1   = ws + 1418880;                        // 512
    float*          cf1   = ws + 1419392;                        // 512
    float*          sf2   = ws + 1419904;                        // 256
    float*          cf2   = ws + 1420160;                        // 256
    float*          fp    = ws;                                  // [2][256][512] (free region)
    float*          P2    = ws + 262144;                         // [2][256][256]

    float* ret = (float*)d_out;            // [256, 800]
    float* f2  = ret + 256 * 800;          // [256, 256]

    k_pre<<<66, 256, 0, stream>>>(
        w3, b3, g3, be3, m3, v3,
        w2, b2, g2, be2, m2, v2,
        w_info, b_info, g_info, be_info, m_info, v_info,
        bf1, gf1, bef1, mf1, vf1,
        bf2, gf2, bef2, mf2, vf2,
        Bh, Bl, bias3, w2q, bias2, cTab4, qTab4, sf1, cf1, sf2, cf2);

    k_edge1b<<<256, 1024, 0, stream>>>(pts, info, cTab4, qTab4,
                                       w2q, bias2, h2h, h2l);

    k_s3<<<256, 256, 0, stream>>>(h2h, h2l, Bh, Bl, bias3, g);

    k_fc1p<<<dim3(8, 16, 2), 256, 0, stream>>>(g, wf1, fp);

    k_fc2p<<<dim3(8, 8, 2), 256, 0, stream>>>(fp, sf1, cf1, wf2, P2);

    k_ep2<<<256, 256, 0, stream>>>(P2, sf2, cf2, f2);

    k_fc3<<<dim3(8, 25), 256, 0, stream>>>(f2, wf3, bf3, ret, 256, 800);
}

// Round 11
// 110.771 us; speedup vs baseline: 2.0309x; 1.0134x over previous
//
#include <hip/hip_runtime.h>
#include <math.h>

#define EPS 1e-5f

typedef __attribute__((ext_vector_type(8))) short short8v;
typedef __attribute__((ext_vector_type(4))) float f32x4;

// ---- bf16 split helpers (RNE) ----
__device__ __forceinline__ unsigned short bf16r(float x) {
    unsigned u = __float_as_uint(x);
    return (unsigned short)((u + 0x7FFFu + ((u >> 16) & 1u)) >> 16);
}
__device__ __forceinline__ float bf2f(unsigned short h) {
    return __uint_as_float(((unsigned)h) << 16);
}

// ---- DPP quad-reduction helpers ----
__device__ __forceinline__ float dpp_xor1_max(float x) {
    int xi = __float_as_int(x);
    int yi = __builtin_amdgcn_update_dpp(xi, xi, 0xB1, 0xF, 0xF, true);
    return fmaxf(x, __int_as_float(yi));
}
__device__ __forceinline__ float dpp_xor2_max(float x) {
    int xi = __float_as_int(x);
    int yi = __builtin_amdgcn_update_dpp(xi, xi, 0x4E, 0xF, 0xF, true);
    return fmaxf(x, __int_as_float(yi));
}

// ---------------------------------------------------------------------------
// k_pre (66 blocks): Bpack (conv3 bf16-split B), w2q/bias2 (conv2 fold),
// cTab4/qTab4 (edge fold), bias3, sf1/cf1, sf2/cf2.
// ---------------------------------------------------------------------------
__global__ __launch_bounds__(256) void k_pre(
    const float* __restrict__ w3, const float* __restrict__ b3,
    const float* __restrict__ g3, const float* __restrict__ be3,
    const float* __restrict__ m3, const float* __restrict__ v3,
    const float* __restrict__ w2, const float* __restrict__ b2,
    const float* __restrict__ g2, const float* __restrict__ be2,
    const float* __restrict__ m2, const float* __restrict__ v2,
    const float* __restrict__ w_info, const float* __restrict__ b_info,
    const float* __restrict__ g_info, const float* __restrict__ be_info,
    const float* __restrict__ m_info, const float* __restrict__ v_info,
    const float* __restrict__ bf1, const float* __restrict__ gf1,
    const float* __restrict__ bef1, const float* __restrict__ mf1,
    const float* __restrict__ vf1,
    const float* __restrict__ bf2, const float* __restrict__ gf2,
    const float* __restrict__ bef2, const float* __restrict__ mf2,
    const float* __restrict__ vf2,
    unsigned short* __restrict__ Bh, unsigned short* __restrict__ Bl,
    float* __restrict__ bias3,
    float4* __restrict__ w2q, float* __restrict__ bias2,
    float4* __restrict__ cTab4, float4* __restrict__ qTab4,
    float* __restrict__ sf1, float* __restrict__ cf1,
    float* __restrict__ sf2, float* __restrict__ cf2)
{
    const int blk = blockIdx.x, tid = threadIdx.x;
    if (blk < 64) {
        const int t = blk * 256 + tid;        // (kt,nt,lane)
        const int kt = t >> 12;
        const int nt = (t >> 6) & 63;
        const int lane = t & 63;
        const int o  = nt * 16 + (lane & 15);
        const int kb = kt * 32 + ((lane >> 4) << 3);
        const float a3 = g3[o] * rsqrtf(v3[o] + EPS);
        unsigned short hi[8], lo[8];
        #pragma unroll
        for (int j = 0; j < 8; ++j) {
            const float wv = a3 * w3[(size_t)o * 128 + kb + j];
            hi[j] = bf16r(wv);
            lo[j] = bf16r(wv - bf2f(hi[j]));
        }
        #pragma unroll
        for (int j = 0; j < 8; ++j) {
            Bh[(size_t)t * 8 + j] = hi[j];
            Bl[(size_t)t * 8 + j] = lo[j];
        }
    } else if (blk == 64) {
        for (int idx = tid; idx < 2048; idx += 256) {
            const int o2 = idx & 127, cq = idx >> 7;
            const float a2 = g2[o2] * rsqrtf(v2[o2] + EPS);
            const float4 w = *(const float4*)(w2 + (size_t)o2 * 64 + cq * 4);
            w2q[cq * 128 + o2] = make_float4(a2 * w.x, a2 * w.y, a2 * w.z, a2 * w.w);
        }
        if (tid < 128) {
            const float a2 = g2[tid] * rsqrtf(v2[tid] + EPS);
            bias2[tid] = a2 * (b2[tid] - m2[tid]) + be2[tid];
        }
    } else {
        if (tid < 64) {
            const int o = tid;
            const float w0 = w_info[o*6+0], w1 = w_info[o*6+1], w2c = w_info[o*6+2];
            const float w3c = w_info[o*6+3], w4 = w_info[o*6+4], w5 = w_info[o*6+5];
            const float a = g_info[o] * rsqrtf(v_info[o] + EPS);
            cTab4[o] = make_float4(a*w0, a*w1, a*w2c, 0.f);
            qTab4[o] = make_float4(a*(w3c-w0), a*(w4-w1), a*(w5-w2c),
                                   a*(b_info[o]-m_info[o]) + be_info[o]);
        }
        for (int c = tid; c < 1024; c += 256) {
            const float a3 = g3[c] * rsqrtf(v3[c] + EPS);
            bias3[c] = a3 * (b3[c] - m3[c]) + be3[c];
        }
        for (int c = tid; c < 512; c += 256) {
            const float s = gf1[c] * rsqrtf(vf1[c] + EPS);
            sf1[c] = s;
            cf1[c] = s * (bf1[c] - mf1[c]) + bef1[c];
        }
        {
            const int c = tid;
            const float s = gf2[c] * rsqrtf(vf2[c] + EPS);
            sf2[c] = s;
            cf2[c] = s * (bf2[c] - mf2[c]) + bef2[c];
        }
    }
}

// ---------------------------------------------------------------------------
// k_edge1b: FUSED edge-conv (6->64) + BN + ReLU + full max over K=520 +
// conv2 (64->128) + BN + ReLU + bf16 hi/lo split for MFMA.
// ONE BLOCK PER b, 1024 thr; wave = n, lane = k-slot.
// R10 lesson (spill signature VGPR=64 / WRITE 30MB): the 80-float per-thread
// state spilled.  FIX: bias is k-INVARIANT -> hoisted out of the max:
//   relu(max_k(w.d + bias)) = max(0, max_k(w.d) + bias)
// so the k-loop holds ONLY acc[16] (init -inf) + c's on the scalar path;
// bias is applied once per tile in the reduction epilogue (~30 live VGPRs).
// ---------------------------------------------------------------------------
__global__ __launch_bounds__(1024) void k_edge1b(
    const float* __restrict__ pts,        // [256,15,3]
    const float* __restrict__ info,       // [256,520,15,3]
    const float4* __restrict__ cTab4,     // [64]
    const float4* __restrict__ qTab4,     // [64]
    const float4* __restrict__ w2q,       // [16][128]
    const float* __restrict__ bias2,      // [128]
    unsigned short* __restrict__ h2h,     // [256][16][128] bf16 hi
    unsigned short* __restrict__ h2l)     // [256][16][128] bf16 lo
{
    __shared__ float ds[23400];           // 93600 B
    __shared__ float part[15][16][17];    // 16320 B
    __shared__ float h1s[960];            // 3840 B   (total 113760 B)

    const int tid = threadIdx.x;
    const int b = blockIdx.x;

    { // coalesced staging of the full 520 k-rows for this b
        const float4* src = (const float4*)(info + (size_t)b * 23400);
        float4* dst = (float4*)ds;
        for (int i = tid; i < 5850; i += 1024) dst[i] = src[i];
    }
    __syncthreads();

    const int wave = tid >> 6, lane = tid & 63;
    if (wave < 15) {
        const int n = wave;
        const float x0 = pts[b*45 + n*3 + 0];
        const float x1 = pts[b*45 + n*3 + 1];
        const float x2 = pts[b*45 + n*3 + 2];

        #pragma unroll
        for (int t = 0; t < 4; ++t) {     // o-tiles of 16
            // wave-uniform coefficients (scalar path); NO bias in the loop
            float c0[16], c1[16], c2[16];
            #pragma unroll
            for (int j = 0; j < 16; ++j) {
                const float4 cv = cTab4[t*16 + j];
                c0[j] = cv.x; c1[j] = cv.y; c2[j] = cv.z;
            }
            float acc[16];
            #pragma unroll
            for (int j = 0; j < 16; ++j) acc[j] = -INFINITY;

            for (int kk = lane; kk < 520; kk += 64) {
                const float* p = ds + kk*45 + n*3;       // per-lane LDS read
                const float d0 = p[0], d1 = p[1], d2 = p[2];
                #pragma unroll
                for (int j = 0; j < 16; ++j)
                    acc[j] = fmaxf(acc[j],
                        fmaf(c0[j], d0, fmaf(c1[j], d1, c2[j] * d2)));
            }
            #pragma unroll
            for (int j = 0; j < 16; ++j) {
                acc[j] = dpp_xor1_max(acc[j]);
                acc[j] = dpp_xor2_max(acc[j]);
            }
            const int q4 = lane >> 2, r4 = lane & 3;
            #pragma unroll
            for (int i = 0; i < 4; ++i) {
                float v = acc[4*i];
                v = (r4 == 1) ? acc[4*i+1] : v;
                v = (r4 == 2) ? acc[4*i+2] : v;
                v = (r4 == 3) ? acc[4*i+3] : v;
                part[n][4*i + r4][q4] = v;
            }
            __builtin_amdgcn_sched_barrier(0);
            asm volatile("s_waitcnt lgkmcnt(0)" ::: "memory");
            __builtin_amdgcn_sched_barrier(0);
            const int o4 = lane >> 2, j4 = lane & 3;
            float m =          part[n][o4][4*j4 + 0];
            m = fmaxf(m, part[n][o4][4*j4 + 1]);
            m = fmaxf(m, part[n][o4][4*j4 + 2]);
            m = fmaxf(m, part[n][o4][4*j4 + 3]);
            m = dpp_xor1_max(m);
            m = dpp_xor2_max(m);
            if (j4 == 0) {
                // bias applied here (hoisted): per-lane o = t*16+o4
                const float4 qv = qTab4[t*16 + o4];
                const float bias = fmaf(qv.x, x0, fmaf(qv.y, x1,
                                   fmaf(qv.z, x2, qv.w)));
                h1s[n*64 + t*16 + o4] = fmaxf(m + bias, 0.f);
            }
            __builtin_amdgcn_sched_barrier(0);
            asm volatile("s_waitcnt lgkmcnt(0)" ::: "memory");
            __builtin_amdgcn_sched_barrier(0);
        }
    }
    __syncthreads();

    // conv2: 16x128 outputs (row 15 = pad 0), bf16 hi/lo split write
    for (int idx = tid; idx < 2048; idx += 1024) {
        const int o2 = idx & 127, n = idx >> 7;   // n: 0..15
        float val = 0.f;
        if (n < 15) {
            float acc = 0.f;
            #pragma unroll
            for (int cq = 0; cq < 16; ++cq) {
                const float4 h4 = *(const float4*)(&h1s[n*64 + cq*4]);
                const float4 w4 = w2q[cq*128 + o2];
                acc = fmaf(w4.x, h4.x, fmaf(w4.y, h4.y,
                      fmaf(w4.z, h4.z, fmaf(w4.w, h4.w, acc))));
            }
            val = fmaxf(acc + bias2[o2], 0.f);
        }
        const unsigned short hi = bf16r(val);
        const unsigned short lo = bf16r(val - bf2f(hi));
        h2h[(size_t)b*2048 + n*128 + o2] = hi;
        h2l[(size_t)b*2048 + n*128 + o2] = lo;
    }
}

// ---------------------------------------------------------------------------
// k_s3: conv3 via bf16x3-split MFMA + global max over N=15.  (validated R9)
// ---------------------------------------------------------------------------
__global__ __launch_bounds__(256) void k_s3(
    const unsigned short* __restrict__ h2h,
    const unsigned short* __restrict__ h2l,
    const unsigned short* __restrict__ Bh,
    const unsigned short* __restrict__ Bl,
    const float* __restrict__ bias3,
    float* __restrict__ gout)         // [256,1024]
{
    const int tid = threadIdx.x;
    const int b = blockIdx.x;
    const int wave = tid >> 6, lane = tid & 63;
    const int arow = lane & 15, agrp = lane >> 4;

    short8v ahi[4], alo[4];
    {
        const unsigned short* Ab = h2h + (size_t)b*2048 + arow*128 + agrp*8;
        const unsigned short* Al = h2l + (size_t)b*2048 + arow*128 + agrp*8;
        #pragma unroll
        for (int kt = 0; kt < 4; ++kt) {
            ahi[kt] = *(const short8v*)(Ab + kt*32);
            alo[kt] = *(const short8v*)(Al + kt*32);
        }
    }

    for (int ntl = 0; ntl < 16; ++ntl) {
        const int nt = wave * 16 + ntl;
        f32x4 a0 = {0.f, 0.f, 0.f, 0.f};
        f32x4 a1 = a0, a2 = a0;
        #pragma unroll
        for (int kt = 0; kt < 4; ++kt) {
            const size_t off = (((size_t)kt*64 + nt)*64 + lane) * 8;
            const short8v bh = *(const short8v*)(Bh + off);
            const short8v bl = *(const short8v*)(Bl + off);
            a0 = __builtin_amdgcn_mfma_f32_16x16x32_bf16(ahi[kt], bh, a0, 0, 0, 0);
            a1 = __builtin_amdgcn_mfma_f32_16x16x32_bf16(ahi[kt], bl, a1, 0, 0, 0);
            a2 = __builtin_amdgcn_mfma_f32_16x16x32_bf16(alo[kt], bh, a2, 0, 0, 0);
        }
        const float r0 = a0[0] + a1[0] + a2[0];
        const float r1 = a0[1] + a1[1] + a2[1];
        const float r2 = a0[2] + a1[2] + a2[2];
        const float r3 = a0[3] + a1[3] + a2[3];
        float m = fmaxf(fmaxf(r0, r1), r2);
        if (agrp != 3) m = fmaxf(m, r3);          // exclude pad row 15
        m = fmaxf(m, __shfl_xor(m, 16));
        m = fmaxf(m, __shfl_xor(m, 32));
        if (lane < 16)
            gout[(size_t)b*1024 + nt*16 + lane] = m + bias3[nt*16 + lane];
    }
}

// ---------------------------------------------------------------------------
// k_fc1p: fc1 split-K=2 raw partials.  grid (8,16,2), 32x32 tile.
// ---------------------------------------------------------------------------
__global__ __launch_bounds__(256) void k_fc1p(
    const float* __restrict__ A,      // g [256][1024]
    const float* __restrict__ W,      // wf1 [512][1024]
    float* __restrict__ P)            // [2][256][512]
{
    __shared__ float As[32][36];
    __shared__ float Ws[32][36];

    const int tid = threadIdx.x;
    const int bm = blockIdx.x * 32, bn = blockIdx.y * 32;
    const int ks = blockIdx.z;
    const int ml = (tid >> 4) * 2, nl = (tid & 15) * 2;
    const int row = tid >> 3, kq = (tid & 7) * 4;

    float acc00 = 0.f, acc01 = 0.f, acc10 = 0.f, acc11 = 0.f;

    for (int k0 = 0; k0 < 512; k0 += 32) {
        const int ch = ks * 512 + k0 + kq;
        const float4 av = *(const float4*)(A + (size_t)(bm + row) * 1024 + ch);
        const float4 wv = *(const float4*)(W + (size_t)(bn + row) * 1024 + ch);
        __syncthreads();
        *(float4*)(&As[row][kq]) = av;
        *(float4*)(&Ws[row][kq]) = wv;
        __syncthreads();
        const float4* a0p = (const float4*)(&As[ml][0]);
        const float4* a1p = (const float4*)(&As[ml + 1][0]);
        const float4* b0p = (const float4*)(&Ws[nl][0]);
        const float4* b1p = (const float4*)(&Ws[nl + 1][0]);
        #pragma unroll
        for (int q = 0; q < 8; ++q) {
            const float4 a0 = a0p[q], a1 = a1p[q], b0 = b0p[q], b1 = b1p[q];
            acc00 = fmaf(a0.x, b0.x, fmaf(a0.y, b0.y, fmaf(a0.z, b0.z, fmaf(a0.w, b0.w, acc00))));
            acc01 = fmaf(a0.x, b1.x, fmaf(a0.y, b1.y, fmaf(a0.z, b1.z, fmaf(a0.w, b1.w, acc01))));
            acc10 = fmaf(a1.x, b0.x, fmaf(a1.y, b0.y, fmaf(a1.z, b0.z, fmaf(a1.w, b0.w, acc10))));
            acc11 = fmaf(a1.x, b1.x, fmaf(a1.y, b1.y, fmaf(a1.z, b1.z, fmaf(a1.w, b1.w, acc11))));
        }
    }
    float* p0 = P + (size_t)ks * 131072 + (size_t)(bm + ml) * 512 + bn + nl;
    p0[0] = acc00; p0[1] = acc01;
    float* p1 = p0 + 512;
    p1[0] = acc10; p1[1] = acc11;
}

// ---------------------------------------------------------------------------
// k_fc2p: fc2 split-K=2; A-tile finishes f1 (BN+ReLU+combine) on the fly.
// ---------------------------------------------------------------------------
__global__ __launch_bounds__(256) void k_fc2p(
    const float* __restrict__ fp,     // [2][256][512]
    const float* __restrict__ sf1, const float* __restrict__ cf1,
    const float* __restrict__ W,      // wf2 [256][512]
    float* __restrict__ P2)           // [2][256][256]
{
    __shared__ float As[32][36];
    __shared__ float Ws[32][36];

    const int tid = threadIdx.x;
    const int bm = blockIdx.x * 32, bn = blockIdx.y * 32;
    const int ks = blockIdx.z;
    const int ml = (tid >> 4) * 2, nl = (tid & 15) * 2;
    const int row = tid >> 3, kq = (tid & 7) * 4;

    float acc00 = 0.f, acc01 = 0.f, acc10 = 0.f, acc11 = 0.f;

    for (int k0 = 0; k0 < 256; k0 += 32) {
        const int ch = ks * 256 + k0 + kq;
        const float4 p0 = *(const float4*)(fp + (size_t)(bm + row) * 512 + ch);
        const float4 p1 = *(const float4*)(fp + 131072 + (size_t)(bm + row) * 512 + ch);
        const float4 s4 = *(const float4*)(sf1 + ch);
        const float4 c4 = *(const float4*)(cf1 + ch);
        float4 av;
        av.x = fmaxf(fmaf(s4.x, p0.x + p1.x, c4.x), 0.f);
        av.y = fmaxf(fmaf(s4.y, p0.y + p1.y, c4.y), 0.f);
        av.z = fmaxf(fmaf(s4.z, p0.z + p1.z, c4.z), 0.f);
        av.w = fmaxf(fmaf(s4.w, p0.w + p1.w, c4.w), 0.f);
        const float4 wv = *(const float4*)(W + (size_t)(bn + row) * 512 + ch);
        __syncthreads();
        *(float4*)(&As[row][kq]) = av;
        *(float4*)(&Ws[row][kq]) = wv;
        __syncthreads();
        const float4* a0p = (const float4*)(&As[ml][0]);
        const float4* a1p = (const float4*)(&As[ml + 1][0]);
        const float4* b0p = (const float4*)(&Ws[nl][0]);
        const float4* b1p = (const float4*)(&Ws[nl + 1][0]);
        #pragma unroll
        for (int q = 0; q < 8; ++q) {
            const float4 a0 = a0p[q], a1 = a1p[q], b0 = b0p[q], b1 = b1p[q];
            acc00 = fmaf(a0.x, b0.x, fmaf(a0.y, b0.y, fmaf(a0.z, b0.z, fmaf(a0.w, b0.w, acc00))));
            acc01 = fmaf(a0.x, b1.x, fmaf(a0.y, b1.y, fmaf(a0.z, b1.z, fmaf(a0.w, b1.w, acc01))));
            acc10 = fmaf(a1.x, b0.x, fmaf(a1.y, b0.y, fmaf(a1.z, b0.z, fmaf(a1.w, b0.w, acc10))));
            acc11 = fmaf(a1.x, b1.x, fmaf(a1.y, b1.y, fmaf(a1.z, b1.z, fmaf(a1.w, b1.w, acc11))));
        }
    }
    float* q0 = P2 + (size_t)ks * 65536 + (size_t)(bm + ml) * 256 + bn + nl;
    q0[0] = acc00; q0[1] = acc01;
    float* q1 = q0 + 256;
    q1[0] = acc10; q1[1] = acc11;
}

// ---------------------------------------------------------------------------
// k_ep2: f2 = relu(sf2*(P2[0]+P2[1]) + cf2)
// ---------------------------------------------------------------------------
__global__ __launch_bounds__(256) void k_ep2(
    const float* __restrict__ P2, const float* __restrict__ sf2,
    const float* __restrict__ cf2, float* __restrict__ f2)
{
    const int i = blockIdx.x * 256 + threadIdx.x;
    const int n = i & 255;
    const float v = P2[i] + P2[65536 + i];
    f2[i] = fmaxf(fmaf(sf2[n], v, cf2[n]), 0.f);
}

// ---------------------------------------------------------------------------
// k_fc3: C = A*W^T + bias
// ---------------------------------------------------------------------------
__global__ __launch_bounds__(256) void k_fc3(
    const float* __restrict__ A, const float* __restrict__ W,
    const float* __restrict__ bias, float* __restrict__ C, int K, int Nc)
{
    __shared__ float As[32][36];
    __shared__ float Ws[32][36];

    const int tid = threadIdx.x;
    const int bm = blockIdx.x * 32, bn = blockIdx.y * 32;
    const int ml = (tid >> 4) * 2, nl = (tid & 15) * 2;
    const int row = tid >> 3, kq = (tid & 7) * 4;

    float acc00 = 0.f, acc01 = 0.f, acc10 = 0.f, acc11 = 0.f;

    for (int k0 = 0; k0 < K; k0 += 32) {
        const float4 av = *(const float4*)(A + (size_t)(bm + row) * K + k0 + kq);
        const float4 wv = *(const float4*)(W + (size_t)(bn + row) * K + k0 + kq);
        __syncthreads();
        *(float4*)(&As[row][kq]) = av;
        *(float4*)(&Ws[row][kq]) = wv;
        __syncthreads();
        const float4* a0p = (const float4*)(&As[ml][0]);
        const float4* a1p = (const float4*)(&As[ml + 1][0]);
        const float4* b0p = (const float4*)(&Ws[nl][0]);
        const float4* b1p = (const float4*)(&Ws[nl + 1][0]);
        #pragma unroll
        for (int q = 0; q < 8; ++q) {
            const float4 a0 = a0p[q], a1 = a1p[q], b0 = b0p[q], b1 = b1p[q];
            acc00 = fmaf(a0.x, b0.x, fmaf(a0.y, b0.y, fmaf(a0.z, b0.z, fmaf(a0.w, b0.w, acc00))));
            acc01 = fmaf(a0.x, b1.x, fmaf(a0.y, b1.y, fmaf(a0.z, b1.z, fmaf(a0.w, b1.w, acc01))));
            acc10 = fmaf(a1.x, b0.x, fmaf(a1.y, b0.y, fmaf(a1.z, b0.z, fmaf(a1.w, b0.w, acc10))));
            acc11 = fmaf(a1.x, b1.x, fmaf(a1.y, b1.y, fmaf(a1.z, b1.z, fmaf(a1.w, b1.w, acc11))));
        }
    }

    const int n0 = bn + nl, n1 = n0 + 1;
    float* cr0 = C + (size_t)(bm + ml) * Nc + n0;
    cr0[0] = acc00 + bias[n0]; cr0[1] = acc01 + bias[n1];
    float* cr1 = C + (size_t)(bm + ml + 1) * Nc + n0;
    cr1[0] = acc10 + bias[n0]; cr1[1] = acc11 + bias[n1];
}

// ---------------------------------------------------------------------------
extern "C" void kernel_launch(void* const* d_in, const int* in_sizes, int n_in,
                              void* d_out, int out_size, void* d_ws, size_t ws_size,
                              hipStream_t stream)
{
    const float* pts     = (const float*)d_in[0];
    const float* info    = (const float*)d_in[2];
    const float* w_info  = (const float*)d_in[3];
    const float* b_info  = (const float*)d_in[4];
    const float* g_info  = (const float*)d_in[5];
    const float* be_info = (const float*)d_in[6];
    const float* m_info  = (const float*)d_in[7];
    const float* v_info  = (const float*)d_in[8];
    const float* w2      = (const float*)d_in[9];
    const float* b2      = (const float*)d_in[10];
    const float* g2      = (const float*)d_in[11];
    const float* be2     = (const float*)d_in[12];
    const float* m2      = (const float*)d_in[13];
    const float* v2      = (const float*)d_in[14];
    const float* w3      = (const float*)d_in[15];
    const float* b3      = (const float*)d_in[16];
    const float* g3      = (const float*)d_in[17];
    const float* be3     = (const float*)d_in[18];
    const float* m3      = (const float*)d_in[19];
    const float* v3      = (const float*)d_in[20];
    const float* wf1     = (const float*)d_in[21];
    const float* bf1     = (const float*)d_in[22];
    const float* gf1     = (const float*)d_in[23];
    const float* bef1    = (const float*)d_in[24];
    const float* mf1     = (const float*)d_in[25];
    const float* vf1     = (const float*)d_in[26];
    const float* wf2     = (const float*)d_in[27];
    const float* bf2     = (const float*)d_in[28];
    const float* gf2     = (const float*)d_in[29];
    const float* bef2    = (const float*)d_in[30];
    const float* mf2     = (const float*)d_in[31];
    const float* vf2     = (const float*)d_in[32];
    const float* wf3     = (const float*)d_in[33];
    const float* bf3     = (const float*)d_in[34];

    float* ws = (float*)d_ws;
    unsigned short* h2h   = (unsigned short*)(ws + 491520);      // 524288 bf16
    unsigned short* h2l   = (unsigned short*)(ws + 753664);      // 524288 bf16
    float*          g     = ws + 1015808;                        // 262144
    unsigned short* Bh    = (unsigned short*)(ws + 1277952);     // 131072 bf16
    unsigned short* Bl    = (unsigned short*)(ws + 1343488);     // 131072 bf16
    float*          bias3 = ws + 1409024;                        // 1024
    float4*         w2q   = (float4*)(ws + 1410048);             // 8192
    float*          bias2 = ws + 1418240;                        // 128
    float4*         cTab4 = (float4*)(ws + 1418368);             // 256
    float4*         qTab4 = (float4*)(ws + 1418624);             // 256
    float*          sf1   = ws + 1418880;                        // 512
    float*          cf1   = ws + 1419392;                        // 512
    float*          sf2   = ws + 1419904;                        // 256
    float*          cf2   = ws + 1420160;                        // 256
    float*          fp    = ws;                                  // [2][256][512] (free region)
    float*          P2    = ws + 262144;                         // [2][256][256]

    float* ret = (float*)d_out;            // [256, 800]
    float* f2  = ret + 256 * 800;          // [256, 256]

    k_pre<<<66, 256, 0, stream>>>(
        w3, b3, g3, be3, m3, v3,
        w2, b2, g2, be2, m2, v2,
        w_info, b_info, g_info, be_info, m_info, v_info,
        bf1, gf1, bef1, mf1, vf1,
        bf2, gf2, bef2, mf2, vf2,
        Bh, Bl, bias3, w2q, bias2, cTab4, qTab4, sf1, cf1, sf2, cf2);

    k_edge1b<<<256, 1024, 0, stream>>>(pts, info, cTab4, qTab4,
                                       w2q, bias2, h2h, h2l);

    k_s3<<<256, 256, 0, stream>>>(h2h, h2l, Bh, Bl, bias3, g);

    k_fc1p<<<dim3(8, 16, 2), 256, 0, stream>>>(g, wf1, fp);

    k_fc2p<<<dim3(8, 8, 2), 256, 0, stream>>>(fp, sf1, cf1, wf2, P2);

    k_ep2<<<256, 256, 0, stream>>>(P2, sf2, cf2, f2);

    k_fc3<<<dim3(8, 25), 256, 0, stream>>>(f2, wf3, bf3, ret, 256, 800);
}